// Round 3
// baseline (2881.061 us; speedup 1.0000x reference)
//
#include <hip/hip_runtime.h>
#include <hip/hip_bf16.h>

#define BB 2
#define NN 32768
#define CC 256
#define SN 16
#define MM 2048          // NN/SN
#define HH 8
#define HD 32
#define QSCALE 0.17677669529663687f   // 1/sqrt(32)
#define AFFSCALE 0.0625f              // C^-0.5

// K1: sf[b,j,c] = mean over 16 tokens
__global__ void k1_sf(const float* __restrict__ x, float* __restrict__ sf) {
    int blk = blockIdx.x;           // b*MM + j
    int b = blk / MM, j = blk % MM;
    int c = threadIdx.x;
    const float* xp = x + ((size_t)(b*NN + j*SN))*CC + c;
    float s = 0.f;
    #pragma unroll
    for (int i = 0; i < SN; ++i) s += xp[i*CC];
    sf[(size_t)blk*CC + c] = s * (1.0f/16.0f);
}

// K2: aff[b,j,i,k] = softmax_k( pix . sf[j+k-1] * scale ), OOB superpixel -> logit 0
__global__ void k2_aff(const float* __restrict__ x, const float* __restrict__ sf,
                       float* __restrict__ aff) {
    int blk = blockIdx.x; int b = blk / MM, j = blk % MM;
    __shared__ float sfl[3][CC];
    __shared__ float xl[SN][CC];
    int tid = threadIdx.x;
    #pragma unroll
    for (int k = 0; k < 3; ++k) {
        int w = j + k - 1;
        sfl[k][tid] = (w >= 0 && w < MM) ? sf[((size_t)b*MM + w)*CC + tid] : 0.f;
    }
    for (int i = 0; i < SN; ++i)
        xl[i][tid] = x[((size_t)(b*NN + j*SN + i))*CC + tid];
    __syncthreads();
    int wave = tid >> 6, lane = tid & 63;
    for (int qi = 0; qi < 4; ++qi) {
        int i = wave*4 + qi;
        float d0=0.f, d1=0.f, d2=0.f;
        #pragma unroll
        for (int cq = 0; cq < 4; ++cq) {
            int c = lane + cq*64;
            float xv = xl[i][c];
            d0 += xv * sfl[0][c];
            d1 += xv * sfl[1][c];
            d2 += xv * sfl[2][c];
        }
        #pragma unroll
        for (int off = 32; off >= 1; off >>= 1) {
            d0 += __shfl_xor(d0, off, 64);
            d1 += __shfl_xor(d1, off, 64);
            d2 += __shfl_xor(d2, off, 64);
        }
        if (lane == 0) {
            float l0 = d0*AFFSCALE, l1 = d1*AFFSCALE, l2 = d2*AFFSCALE;
            float mx = fmaxf(l0, fmaxf(l1, l2));
            float e0 = __expf(l0-mx), e1 = __expf(l1-mx), e2 = __expf(l2-mx);
            float inv = 1.0f/(e0+e1+e2);
            size_t base = ((size_t)blk*SN + i)*3;
            aff[base+0] = e0*inv; aff[base+1] = e1*inv; aff[base+2] = e2*inv;
        }
    }
}

// K3: sf2[b,j,c] = (fold of aff-weighted pixel sums) / (aff_sum + 1e-12)
__global__ void k3_sf2(const float* __restrict__ x, const float* __restrict__ aff,
                       float* __restrict__ sf2) {
    int blk = blockIdx.x; int b = blk / MM, j = blk % MM;
    int c = threadIdx.x;
    __shared__ float al[3][SN];
    __shared__ float asum_sh;
    if (threadIdx.x < 48) {
        int k = threadIdx.x / 16, i = threadIdx.x % 16;
        int w = (k == 0) ? j+1 : (k == 1) ? j : j-1;
        al[k][i] = (w >= 0 && w < MM) ? aff[(((size_t)b*MM + w)*SN + i)*3 + k] : 0.f;
    }
    __syncthreads();
    if (threadIdx.x == 0) {
        float s = 0.f;
        for (int t = 0; t < 48; ++t) s += al[t/16][t%16];
        asum_sh = s;
    }
    float acc = 0.f;
    #pragma unroll
    for (int k = 0; k < 3; ++k) {
        int w = (k==0)? j+1 : (k==1)? j : j-1;
        if (w < 0 || w >= MM) continue;
        const float* xp = x + ((size_t)(b*NN + w*SN))*CC + c;
        #pragma unroll
        for (int i = 0; i < SN; ++i) acc += xp[i*CC] * al[k][i];
    }
    __syncthreads();
    sf2[((size_t)b*MM + j)*CC + c] = acc / (asum_sh + 1e-12f);
}

// K4a (brute force): one thread per (b, o, m): qkv row
__global__ void k4a_qkv(const float* __restrict__ sf2, const float* __restrict__ wqkv,
                        float* __restrict__ qb, float* __restrict__ kb, float* __restrict__ vb) {
    int idx = blockIdx.x*256 + threadIdx.x;          // b*768*2048 + o*2048 + m
    int m = idx & (MM-1);
    int rest = idx >> 11;                             // b*768 + o
    int o = rest % (3*CC);
    int b = rest / (3*CC);
    const float* w = wqkv + (size_t)o*CC;
    const float* s = sf2 + ((size_t)b*MM + m)*CC;
    float acc = 0.f;
    #pragma unroll 8
    for (int c = 0; c < CC; ++c) acc += w[c]*s[c];
    int h = o / 96, r = o % 96;
    size_t base = (((size_t)b*HH + h)*MM + m)*HD;
    if (r < 32) qb[base + r] = acc * QSCALE;
    else if (r < 64) kb[base + (r-32)] = acc;
    else vb[base + (r-64)] = acc;
}

// K4b (brute force): one thread per (bh, mm): rsinv = 1 / sum_nn exp(k_mm . q_nn)
__global__ void k4b_ses(const float* __restrict__ qb, const float* __restrict__ kb,
                        float* __restrict__ rsinv) {
    int idx = blockIdx.x*256 + threadIdx.x;          // bh*2048 + mm
    int mm = idx & (MM-1);
    int bh = idx >> 11;
    const float* kr = kb + ((size_t)bh*MM + mm)*HD;
    float k0[HD];
    #pragma unroll
    for (int d = 0; d < HD; ++d) k0[d] = kr[d];
    const float* qbase = qb + (size_t)bh*MM*HD;
    float sum = 0.f;
    for (int nn = 0; nn < MM; ++nn) {
        const float* qr = qbase + (size_t)nn*HD;
        float s = 0.f;
        #pragma unroll
        for (int d = 0; d < HD; ++d) s += k0[d]*qr[d];
        sum += __expf(s);
    }
    rsinv[idx] = 1.0f / sum;
}

// K4c (brute force): one thread per (bh, nn): attnout[b, nn, h*32+d] = sum_mm v*exp*rsinv
__global__ void k4c_out(const float* __restrict__ qb, const float* __restrict__ kb,
                        const float* __restrict__ vb, const float* __restrict__ rsinv,
                        float* __restrict__ attnout) {
    int idx = blockIdx.x*256 + threadIdx.x;          // bh*2048 + nn
    int nn = idx & (MM-1);
    int bh = idx >> 11;
    int b = bh / HH, h = bh % HH;
    float q0[HD], acc[HD];
    const float* qr = qb + ((size_t)bh*MM + nn)*HD;
    #pragma unroll
    for (int d = 0; d < HD; ++d) { q0[d] = qr[d]; acc[d] = 0.f; }
    const float* kbase = kb + (size_t)bh*MM*HD;
    const float* vbase = vb + (size_t)bh*MM*HD;
    const float* rbase = rsinv + (size_t)bh*MM;
    for (int mm = 0; mm < MM; ++mm) {
        const float* kr = kbase + (size_t)mm*HD;
        float s = 0.f;
        #pragma unroll
        for (int d = 0; d < HD; ++d) s += q0[d]*kr[d];
        float w = __expf(s) * rbase[mm];
        const float* vr = vbase + (size_t)mm*HD;
        #pragma unroll
        for (int d = 0; d < HD; ++d) acc[d] += w * vr[d];
    }
    float* op = attnout + ((size_t)b*MM + nn)*CC + h*HD;
    #pragma unroll
    for (int d = 0; d < HD; ++d) op[d] = acc[d];
}

// K5 (brute force): one thread per (b, o, m): sf2r[b,o,m] = Wproj @ attnout + bproj
__global__ void k5_proj(const float* __restrict__ attnout, const float* __restrict__ wproj,
                        const float* __restrict__ bproj, float* __restrict__ sf2r) {
    int idx = blockIdx.x*256 + threadIdx.x;          // (b*256 + o)*2048 + m
    int m = idx & (MM-1);
    int rest = idx >> 11;
    int o = rest % CC;
    int b = rest / CC;
    const float* w = wproj + (size_t)o*CC;
    const float* a = attnout + ((size_t)b*MM + m)*CC;
    float acc = 0.f;
    #pragma unroll 8
    for (int c = 0; c < CC; ++c) acc += w[c]*a[c];
    sf2r[((size_t)b*CC + o)*MM + m] = acc + bproj[o];
}

// K6: out[b,c,j*16+i] = sum_k sf2r[b,c,j+k-1]*aff[b,j,i,k]  (fp32 output)
__global__ void k6_final(const float* __restrict__ sf2r, const float* __restrict__ aff,
                         float* __restrict__ out) {
    int blk = blockIdx.x;
    int b = blk / (MM/16), jt = blk % (MM/16);
    int jb = jt*16;
    int tid = threadIdx.x;               // 256 tokens
    int jl = tid >> 4, il = tid & 15;
    int j = jb + jl;
    size_t abase = (((size_t)b*MM + j)*SN + il)*3;
    float a0 = aff[abase], a1 = aff[abase+1], a2 = aff[abase+2];
    __shared__ float stile[16][19];
    int t = jb*SN + tid;
    for (int ct = 0; ct < 16; ++ct) {
        for (int idx = tid; idx < 16*18; idx += 256) {
            int cl = idx / 18, jo = idx % 18;
            int jj = jb - 1 + jo;
            stile[cl][jo] = (jj >= 0 && jj < MM) ? sf2r[((size_t)b*CC + ct*16 + cl)*MM + jj] : 0.f;
        }
        __syncthreads();
        #pragma unroll
        for (int cl = 0; cl < 16; ++cl) {
            float v = stile[cl][jl]*a0 + stile[cl][jl+1]*a1 + stile[cl][jl+2]*a2;
            out[((size_t)b*CC + ct*16 + cl)*NN + t] = v;
        }
        __syncthreads();
    }
}

extern "C" void kernel_launch(void* const* d_in, const int* in_sizes, int n_in,
                              void* d_out, int out_size, void* d_ws, size_t ws_size,
                              hipStream_t stream) {
    // Select inputs by size (all four sizes are distinct) — robust to ordering.
    const float *x = nullptr, *wqkv = nullptr, *wproj = nullptr, *bproj = nullptr;
    for (int i = 0; i < n_in; ++i) {
        int sz = in_sizes[i];
        if (sz == BB*NN*CC)        x     = (const float*)d_in[i];
        else if (sz == 3*CC*CC)    wqkv  = (const float*)d_in[i];
        else if (sz == CC*CC)      wproj = (const float*)d_in[i];
        else if (sz == CC)         bproj = (const float*)d_in[i];
    }
    float* out = (float*)d_out;    // reference output dtype is float32
    char* ws = (char*)d_ws;
    const size_t MB = 1024*1024;
    // Compact, reuse-heavy workspace: 17.2 MiB total
    float* aff     = (float*)(ws);            // 0.75 MiB, live k2->k6
    float* regA    = (float*)(ws + 1*MB);     // 4 MiB: sf (k1->k2), sf2 (k3->k4a), attnout (k4c->k5)
    float* qb      = (float*)(ws + 5*MB);     // 4 MiB (k4a->k4c); then sf2r (k5->k6)
    float* kb      = (float*)(ws + 9*MB);     // 4 MiB
    float* vb      = (float*)(ws + 13*MB);    // 4 MiB
    float* rsinv   = (float*)(ws + 17*MB);    // 128 KiB
    float* sf      = regA;
    float* sf2     = regA;
    float* attnout = regA;
    float* sf2r    = qb;

    k1_sf  <<<BB*MM, 256, 0, stream>>>(x, sf);
    k2_aff <<<BB*MM, 256, 0, stream>>>(x, sf, aff);
    k3_sf2 <<<BB*MM, 256, 0, stream>>>(x, aff, sf2);
    k4a_qkv<<<BB*3*CC*MM/256, 256, 0, stream>>>(sf2, wqkv, qb, kb, vb);
    k4b_ses<<<BB*HH*MM/256, 256, 0, stream>>>(qb, kb, rsinv);
    k4c_out<<<BB*HH*MM/256, 256, 0, stream>>>(qb, kb, vb, rsinv, attnout);
    k5_proj<<<BB*CC*MM/256, 256, 0, stream>>>(attnout, wproj, bproj, sf2r);
    k6_final<<<BB*(MM/16), 256, 0, stream>>>(sf2r, aff, out);
}

// Round 4
// 676.853 us; speedup vs baseline: 4.2566x; 4.2566x over previous
//
#include <hip/hip_runtime.h>
#include <hip/hip_bf16.h>

#define BB 2
#define NN 32768
#define CC 256
#define SN 16
#define MM 2048          // NN/SN
#define HH 8
#define HD 32
#define PP1 8            // nn-partitions for denominator pass
#define PPB 4            // mm-partitions for output pass
#define QSCALE 0.17677669529663687f   // 1/sqrt(32)
#define AFFSCALE 0.0625f              // C^-0.5

// K1: sf[b,j,c] = mean over 16 tokens
__global__ void k1_sf(const float* __restrict__ x, float* __restrict__ sf) {
    int blk = blockIdx.x;           // b*MM + j
    int b = blk / MM, j = blk % MM;
    int c = threadIdx.x;
    const float* xp = x + ((size_t)(b*NN + j*SN))*CC + c;
    float s = 0.f;
    #pragma unroll
    for (int i = 0; i < SN; ++i) s += xp[i*CC];
    sf[(size_t)blk*CC + c] = s * (1.0f/16.0f);
}

// K2: aff[b,j,i,k] = softmax_k( pix . sf[j+k-1] * scale ), OOB superpixel -> logit 0
__global__ void k2_aff(const float* __restrict__ x, const float* __restrict__ sf,
                       float* __restrict__ aff) {
    int blk = blockIdx.x; int b = blk / MM, j = blk % MM;
    __shared__ float sfl[3][CC];
    __shared__ float xl[SN][CC];
    int tid = threadIdx.x;
    #pragma unroll
    for (int k = 0; k < 3; ++k) {
        int w = j + k - 1;
        sfl[k][tid] = (w >= 0 && w < MM) ? sf[((size_t)b*MM + w)*CC + tid] : 0.f;
    }
    for (int i = 0; i < SN; ++i)
        xl[i][tid] = x[((size_t)(b*NN + j*SN + i))*CC + tid];
    __syncthreads();
    int wave = tid >> 6, lane = tid & 63;
    for (int qi = 0; qi < 4; ++qi) {
        int i = wave*4 + qi;
        float d0=0.f, d1=0.f, d2=0.f;
        #pragma unroll
        for (int cq = 0; cq < 4; ++cq) {
            int c = lane + cq*64;
            float xv = xl[i][c];
            d0 += xv * sfl[0][c];
            d1 += xv * sfl[1][c];
            d2 += xv * sfl[2][c];
        }
        #pragma unroll
        for (int off = 32; off >= 1; off >>= 1) {
            d0 += __shfl_xor(d0, off, 64);
            d1 += __shfl_xor(d1, off, 64);
            d2 += __shfl_xor(d2, off, 64);
        }
        if (lane == 0) {
            float l0 = d0*AFFSCALE, l1 = d1*AFFSCALE, l2 = d2*AFFSCALE;
            float mx = fmaxf(l0, fmaxf(l1, l2));
            float e0 = __expf(l0-mx), e1 = __expf(l1-mx), e2 = __expf(l2-mx);
            float inv = 1.0f/(e0+e1+e2);
            size_t base = ((size_t)blk*SN + i)*3;
            aff[base+0] = e0*inv; aff[base+1] = e1*inv; aff[base+2] = e2*inv;
        }
    }
}

// K3: sf2[b,j,c] = (fold of aff-weighted pixel sums) / (aff_sum + 1e-12)
__global__ void k3_sf2(const float* __restrict__ x, const float* __restrict__ aff,
                       float* __restrict__ sf2) {
    int blk = blockIdx.x; int b = blk / MM, j = blk % MM;
    int c = threadIdx.x;
    __shared__ float al[3][SN];
    __shared__ float asum_sh;
    if (threadIdx.x < 48) {
        int k = threadIdx.x / 16, i = threadIdx.x % 16;
        int w = (k == 0) ? j+1 : (k == 1) ? j : j-1;
        al[k][i] = (w >= 0 && w < MM) ? aff[(((size_t)b*MM + w)*SN + i)*3 + k] : 0.f;
    }
    __syncthreads();
    if (threadIdx.x == 0) {
        float s = 0.f;
        for (int t = 0; t < 48; ++t) s += al[t/16][t%16];
        asum_sh = s;
    }
    float acc = 0.f;
    #pragma unroll
    for (int k = 0; k < 3; ++k) {
        int w = (k==0)? j+1 : (k==1)? j : j-1;
        if (w < 0 || w >= MM) continue;
        const float* xp = x + ((size_t)(b*NN + w*SN))*CC + c;
        #pragma unroll
        for (int i = 0; i < SN; ++i) acc += xp[i*CC] * al[k][i];
    }
    __syncthreads();
    sf2[((size_t)b*MM + j)*CC + c] = acc / (asum_sh + 1e-12f);
}

// K4a (LDS-tiled): 16 m-rows per block, all 768 outputs
__global__ void k4a_qkv(const float* __restrict__ sf2, const float* __restrict__ wqkv,
                        float* __restrict__ qb, float* __restrict__ kb, float* __restrict__ vb) {
    int blk = blockIdx.x;
    int b = blk / (MM/16), mt = blk % (MM/16);
    int mm0 = mt * 16;
    __shared__ float sl[16][CC+1];
    __shared__ float wl[16][CC+1];
    int tid = threadIdx.x;
    for (int idx = tid; idx < 16*CC; idx += 256) {
        int r = idx >> 8, c = idx & 255;
        sl[r][c] = sf2[((size_t)b*MM + mm0 + r)*CC + c];
    }
    __syncthreads();
    int ml = tid & 15, og = tid >> 4;
    for (int ob = 0; ob < 3*CC; ob += 16) {
        for (int idx = tid; idx < 16*CC; idx += 256) {
            int r = idx >> 8, c = idx & 255;
            wl[r][c] = wqkv[(size_t)(ob + r)*CC + c];
        }
        __syncthreads();
        float acc = 0.f;
        for (int c = 0; c < CC; ++c) acc += wl[og][c] * sl[ml][c];
        int o = ob + og;
        int h = o / 96, r = o % 96;
        int mm = mm0 + ml;
        size_t base = (((size_t)b*HH + h)*MM + mm)*HD;
        if (r < 32) qb[base + r] = acc * QSCALE;
        else if (r < 64) kb[base + (r-32)] = acc;
        else vb[base + (r-64)] = acc;
        __syncthreads();
    }
}

// K4b: partial denominators ses[p][bh][mm] = sum over nn-partition of exp(k_mm . q_nn)
__global__ void k4b_ses(const float* __restrict__ qb, const float* __restrict__ kb,
                        float* __restrict__ ses) {
    int bx = blockIdx.x;             // bh*(MM/256) + mchunk
    int p = blockIdx.y;
    int bh = bx >> 3;                // MM/256 = 8 chunks
    int mchunk = bx & 7;
    int tid = threadIdx.x;           // 256
    int mm = mchunk*256 + tid;
    float k0[HD];
    const float* kr = kb + ((size_t)bh*MM + mm)*HD;
    #pragma unroll
    for (int d = 0; d < HD; ++d) k0[d] = kr[d];
    __shared__ float ql[256][HD];
    int nn0 = p * (MM/PP1);          // 256 nn per partition
    for (int idx = tid; idx < 256*HD; idx += 256) {
        int r = idx >> 5, d = idx & 31;
        ql[r][d] = qb[((size_t)bh*MM + nn0 + r)*HD + d];
    }
    __syncthreads();
    float sum = 0.f;
    for (int r = 0; r < 256; ++r) {
        float s = 0.f;
        #pragma unroll
        for (int d = 0; d < HD; ++d) s += k0[d]*ql[r][d];
        sum += __expf(s);
    }
    ses[((size_t)p*BB*HH + bh)*MM + mm] = sum;
}

// K4bm: merge partial denominators -> rsinv
__global__ void k4bm(const float* __restrict__ ses, float* __restrict__ rsinv) {
    int e = blockIdx.x*256 + threadIdx.x;
    float s = 0.f;
    #pragma unroll
    for (int p = 0; p < PP1; ++p) s += ses[(size_t)p*(BB*HH*MM) + e];
    rsinv[e] = 1.0f / s;
}

// K4c: partial outputs part[p][b][nn][h*32+d] over mm-partition
__global__ void k4c_out(const float* __restrict__ qb, const float* __restrict__ kb,
                        const float* __restrict__ vb, const float* __restrict__ rsinv,
                        float* __restrict__ part) {
    int bx = blockIdx.x;
    int bh = bx / (MM/128), nt = bx % (MM/128);
    int p = blockIdx.y;
    int tid = threadIdx.x;               // 128
    int nn = nt*128 + tid;
    int b = bh / HH, h = bh % HH;
    float q0[HD], acc[HD];
    const float* qr = qb + ((size_t)bh*MM + nn)*HD;
    #pragma unroll
    for (int d = 0; d < HD; ++d) { q0[d] = qr[d]; acc[d] = 0.f; }
    __shared__ float kl[32][HD];
    __shared__ float vl[32][HD];
    __shared__ float rl[32];
    int mm0 = p*(MM/PPB);                // 512 mm per partition
    for (int t = 0; t < (MM/PPB); t += 32) {
        for (int idx = tid; idx < 32*HD; idx += 128) {
            int r = idx >> 5, d = idx & 31;
            kl[r][d] = kb[((size_t)bh*MM + mm0 + t + r)*HD + d];
            vl[r][d] = vb[((size_t)bh*MM + mm0 + t + r)*HD + d];
        }
        if (tid < 32) rl[tid] = rsinv[(size_t)bh*MM + mm0 + t + tid];
        __syncthreads();
        for (int r = 0; r < 32; ++r) {
            float s = 0.f;
            #pragma unroll
            for (int d = 0; d < HD; ++d) s += q0[d]*kl[r][d];
            float w = __expf(s) * rl[r];
            #pragma unroll
            for (int d = 0; d < HD; ++d) acc[d] += w * vl[r][d];
        }
        __syncthreads();
    }
    float* op = part + (((size_t)p*BB + b)*MM + nn)*CC + h*HD;
    #pragma unroll
    for (int d = 0; d < HD; ++d) op[d] = acc[d];
}

// K4d: reduce partials -> attnout (B,M,C)
__global__ void k4d_red(const float* __restrict__ part, float* __restrict__ attnout) {
    size_t e = (size_t)blockIdx.x*256 + threadIdx.x;
    float s = 0.f;
    #pragma unroll
    for (int p = 0; p < PPB; ++p) s += part[(size_t)p*((size_t)BB*MM*CC) + e];
    attnout[e] = s;
}

// K5 (LDS-tiled): sf2r[b,o,mm] = Wproj @ attnout + bproj
__global__ void k5_proj(const float* __restrict__ attnout, const float* __restrict__ wproj,
                        const float* __restrict__ bproj, float* __restrict__ sf2r) {
    int blk = blockIdx.x; int b = blk / (MM/16), mt = blk % (MM/16);
    int mm0 = mt*16;
    __shared__ float al[16][CC+1];
    __shared__ float wl[16][CC+1];
    int tid = threadIdx.x;
    for (int idx = tid; idx < 16*CC; idx += 256) {
        int r = idx >> 8, c = idx & 255;
        al[r][c] = attnout[((size_t)b*MM + mm0 + r)*CC + c];
    }
    __syncthreads();
    int ml = tid & 15, og = tid >> 4;
    for (int ob = 0; ob < CC; ob += 16) {
        for (int idx = tid; idx < 16*CC; idx += 256) {
            int r = idx >> 8, c = idx & 255;
            wl[r][c] = wproj[(size_t)(ob + r)*CC + c];
        }
        __syncthreads();
        float acc = 0.f;
        for (int c = 0; c < CC; ++c) acc += wl[og][c]*al[ml][c];
        int o = ob + og;
        sf2r[((size_t)b*CC + o)*MM + mm0 + ml] = acc + bproj[o];
        __syncthreads();
    }
}

// K6: out[b,c,j*16+i] = sum_k sf2r[b,c,j+k-1]*aff[b,j,i,k]  (fp32 output)
__global__ void k6_final(const float* __restrict__ sf2r, const float* __restrict__ aff,
                         float* __restrict__ out) {
    int blk = blockIdx.x;
    int b = blk / (MM/16), jt = blk % (MM/16);
    int jb = jt*16;
    int tid = threadIdx.x;               // 256 tokens
    int jl = tid >> 4, il = tid & 15;
    int j = jb + jl;
    size_t abase = (((size_t)b*MM + j)*SN + il)*3;
    float a0 = aff[abase], a1 = aff[abase+1], a2 = aff[abase+2];
    __shared__ float stile[16][19];
    int t = jb*SN + tid;
    for (int ct = 0; ct < 16; ++ct) {
        for (int idx = tid; idx < 16*18; idx += 256) {
            int cl = idx / 18, jo = idx % 18;
            int jj = jb - 1 + jo;
            stile[cl][jo] = (jj >= 0 && jj < MM) ? sf2r[((size_t)b*CC + ct*16 + cl)*MM + jj] : 0.f;
        }
        __syncthreads();
        #pragma unroll
        for (int cl = 0; cl < 16; ++cl) {
            float v = stile[cl][jl]*a0 + stile[cl][jl+1]*a1 + stile[cl][jl+2]*a2;
            out[((size_t)b*CC + ct*16 + cl)*NN + t] = v;
        }
        __syncthreads();
    }
}

extern "C" void kernel_launch(void* const* d_in, const int* in_sizes, int n_in,
                              void* d_out, int out_size, void* d_ws, size_t ws_size,
                              hipStream_t stream) {
    const float *x = nullptr, *wqkv = nullptr, *wproj = nullptr, *bproj = nullptr;
    for (int i = 0; i < n_in; ++i) {
        int sz = in_sizes[i];
        if (sz == BB*NN*CC)        x     = (const float*)d_in[i];
        else if (sz == 3*CC*CC)    wqkv  = (const float*)d_in[i];
        else if (sz == CC*CC)      wproj = (const float*)d_in[i];
        else if (sz == CC)         bproj = (const float*)d_in[i];
    }
    float* out = (float*)d_out;    // reference output dtype is float32
    char* ws = (char*)d_ws;
    const size_t MB = 1024*1024;
    // Workspace layout (35 MiB total)
    float* aff     = (float*)(ws);            // 0.75 MiB (k2 -> k6)
    float* regA    = (float*)(ws + 1*MB);     // 4 MiB: sf (k1->k2), sf2 (k3->k4a), attnout (k4d->k5)
    float* qb      = (float*)(ws + 5*MB);     // 4 MiB (k4a->k4c); reused as sf2r (k5->k6)
    float* kb      = (float*)(ws + 9*MB);     // 4 MiB
    float* vb      = (float*)(ws + 13*MB);    // 4 MiB
    float* ses     = (float*)(ws + 17*MB);    // 1 MiB (PP1 partials)
    float* rsinv   = (float*)(ws + 18*MB);    // 128 KiB
    float* part    = (float*)(ws + 19*MB);    // 16 MiB (PPB partials)
    float* sf      = regA;
    float* sf2     = regA;
    float* attnout = regA;
    float* sf2r    = qb;

    k1_sf  <<<BB*MM, 256, 0, stream>>>(x, sf);
    k2_aff <<<BB*MM, 256, 0, stream>>>(x, sf, aff);
    k3_sf2 <<<BB*MM, 256, 0, stream>>>(x, aff, sf2);
    k4a_qkv<<<BB*(MM/16), 256, 0, stream>>>(sf2, wqkv, qb, kb, vb);
    k4b_ses<<<dim3(BB*HH*(MM/256), PP1), 256, 0, stream>>>(qb, kb, ses);
    k4bm   <<<(BB*HH*MM)/256, 256, 0, stream>>>(ses, rsinv);
    k4c_out<<<dim3(BB*HH*(MM/128), PPB), 128, 0, stream>>>(qb, kb, vb, rsinv, part);
    k4d_red<<<(int)(((size_t)BB*MM*CC)/256), 256, 0, stream>>>(part, attnout);
    k5_proj<<<BB*(MM/16), 256, 0, stream>>>(attnout, wproj, bproj, sf2r);
    k6_final<<<BB*(MM/16), 256, 0, stream>>>(sf2r, aff, out);
}

// Round 5
// 337.456 us; speedup vs baseline: 8.5376x; 2.0058x over previous
//
#include <hip/hip_runtime.h>
#include <hip/hip_bf16.h>

#define BB 2
#define NN 32768
#define CC 256
#define SN 16
#define MM 2048          // NN/SN
#define HH 8
#define HD 32
#define QSCALE 0.17677669529663687f   // 1/sqrt(32)
#define AFFSCALE 0.0625f              // C^-0.5

typedef unsigned short u16;
typedef __attribute__((ext_vector_type(8))) short bf16x8;
typedef __attribute__((ext_vector_type(4))) float f32x4;

// RNE float->bf16 bits
__device__ __forceinline__ u16 f2bfu(float x) {
    unsigned u = __float_as_uint(x);
    u = (u + 0x7fff + ((u >> 16) & 1)) >> 16;
    return (u16)u;
}

// K1: sf[b,j,c] = mean over 16 tokens
__global__ void k1_sf(const float* __restrict__ x, float* __restrict__ sf) {
    int blk = blockIdx.x;           // b*MM + j
    int b = blk / MM, j = blk % MM;
    int c = threadIdx.x;
    const float* xp = x + ((size_t)(b*NN + j*SN))*CC + c;
    float s = 0.f;
    #pragma unroll
    for (int i = 0; i < SN; ++i) s += xp[i*CC];
    sf[(size_t)blk*CC + c] = s * (1.0f/16.0f);
}

// K2: aff[b,j,i,k] = softmax_k( pix . sf[j+k-1] * scale ), OOB superpixel -> logit 0
__global__ void k2_aff(const float* __restrict__ x, const float* __restrict__ sf,
                       float* __restrict__ aff) {
    int blk = blockIdx.x; int b = blk / MM, j = blk % MM;
    __shared__ float sfl[3][CC];
    __shared__ float xl[SN][CC];
    int tid = threadIdx.x;
    #pragma unroll
    for (int k = 0; k < 3; ++k) {
        int w = j + k - 1;
        sfl[k][tid] = (w >= 0 && w < MM) ? sf[((size_t)b*MM + w)*CC + tid] : 0.f;
    }
    for (int i = 0; i < SN; ++i)
        xl[i][tid] = x[((size_t)(b*NN + j*SN + i))*CC + tid];
    __syncthreads();
    int wave = tid >> 6, lane = tid & 63;
    for (int qi = 0; qi < 4; ++qi) {
        int i = wave*4 + qi;
        float d0=0.f, d1=0.f, d2=0.f;
        #pragma unroll
        for (int cq = 0; cq < 4; ++cq) {
            int c = lane + cq*64;
            float xv = xl[i][c];
            d0 += xv * sfl[0][c];
            d1 += xv * sfl[1][c];
            d2 += xv * sfl[2][c];
        }
        #pragma unroll
        for (int off = 32; off >= 1; off >>= 1) {
            d0 += __shfl_xor(d0, off, 64);
            d1 += __shfl_xor(d1, off, 64);
            d2 += __shfl_xor(d2, off, 64);
        }
        if (lane == 0) {
            float l0 = d0*AFFSCALE, l1 = d1*AFFSCALE, l2 = d2*AFFSCALE;
            float mx = fmaxf(l0, fmaxf(l1, l2));
            float e0 = __expf(l0-mx), e1 = __expf(l1-mx), e2 = __expf(l2-mx);
            float inv = 1.0f/(e0+e1+e2);
            size_t base = ((size_t)blk*SN + i)*3;
            aff[base+0] = e0*inv; aff[base+1] = e1*inv; aff[base+2] = e2*inv;
        }
    }
}

// K3: sf2[b,j,c] = (fold of aff-weighted pixel sums) / (aff_sum + 1e-12)
__global__ void k3_sf2(const float* __restrict__ x, const float* __restrict__ aff,
                       float* __restrict__ sf2) {
    int blk = blockIdx.x; int b = blk / MM, j = blk % MM;
    int c = threadIdx.x;
    __shared__ float al[3][SN];
    __shared__ float asum_sh;
    if (threadIdx.x < 48) {
        int k = threadIdx.x / 16, i = threadIdx.x % 16;
        int w = (k == 0) ? j+1 : (k == 1) ? j : j-1;
        al[k][i] = (w >= 0 && w < MM) ? aff[(((size_t)b*MM + w)*SN + i)*3 + k] : 0.f;
    }
    __syncthreads();
    if (threadIdx.x == 0) {
        float s = 0.f;
        for (int t = 0; t < 48; ++t) s += al[t/16][t%16];
        asum_sh = s;
    }
    float acc = 0.f;
    #pragma unroll
    for (int k = 0; k < 3; ++k) {
        int w = (k==0)? j+1 : (k==1)? j : j-1;
        if (w < 0 || w >= MM) continue;
        const float* xp = x + ((size_t)(b*NN + w*SN))*CC + c;
        #pragma unroll
        for (int i = 0; i < SN; ++i) acc += xp[i*CC] * al[k][i];
    }
    __syncthreads();
    sf2[((size_t)b*MM + j)*CC + c] = acc / (asum_sh + 1e-12f);
}

// K4a (LDS-tiled fp32 GEMM): emits bf16 q (pre-scaled), k, and vT
__global__ void k4a_qkv(const float* __restrict__ sf2, const float* __restrict__ wqkv,
                        u16* __restrict__ qh, u16* __restrict__ kh, u16* __restrict__ vth) {
    int blk = blockIdx.x;
    int b = blk / (MM/16), mt = blk % (MM/16);
    int mm0 = mt * 16;
    __shared__ float sl[16][CC+1];
    __shared__ float wl[16][CC+1];
    int tid = threadIdx.x;
    for (int idx = tid; idx < 16*CC; idx += 256) {
        int r = idx >> 8, c = idx & 255;
        sl[r][c] = sf2[((size_t)b*MM + mm0 + r)*CC + c];
    }
    __syncthreads();
    int ml = tid & 15, og = tid >> 4;
    for (int ob = 0; ob < 3*CC; ob += 16) {
        for (int idx = tid; idx < 16*CC; idx += 256) {
            int r = idx >> 8, c = idx & 255;
            wl[r][c] = wqkv[(size_t)(ob + r)*CC + c];
        }
        __syncthreads();
        float acc = 0.f;
        for (int c = 0; c < CC; ++c) acc += wl[og][c] * sl[ml][c];
        int o = ob + og;
        int h = o / 96, r = o % 96;
        int mm = mm0 + ml;
        int bh = b*HH + h;
        if (r < 32)      qh[((size_t)bh*MM + mm)*HD + r]        = f2bfu(acc * QSCALE);
        else if (r < 64) kh[((size_t)bh*MM + mm)*HD + (r-32)]   = f2bfu(acc);
        else             vth[((size_t)bh*HD + (r-64))*MM + mm]  = f2bfu(acc);
        __syncthreads();
    }
}

// K4b (MFMA): denom[bh][mm] = sum over all nn of exp(k_mm . q_nn)
// block = (bh, 64-mm tile), 4 waves; wave w owns mm-subtile w.
__global__ void k4b_mfma(const u16* __restrict__ qh, const u16* __restrict__ kh,
                         float* __restrict__ denom) {
    int bx = blockIdx.x;
    int bh = bx >> 5;                 // MM/64 = 32 tiles
    int mt = bx & 31;
    int mm0 = mt * 64;
    int tid = threadIdx.x, w = tid >> 6, l = tid & 63;
    // A-frag (K rows), loop-invariant: row = mm0 + w*16 + (l&15), kchunk = (l>>4)*8
    bf16x8 af = *(const bf16x8*)&kh[((size_t)bh*MM + mm0 + w*16 + (l&15))*HD + ((l>>4)<<3)];
    __shared__ u16 Qlds[64][40];
    float rs0=0.f, rs1=0.f, rs2=0.f, rs3=0.f;
    for (int nn0 = 0; nn0 < MM; nn0 += 64) {
        __syncthreads();
        {   // stage Q-tile (64 rows x 32)
            int r = tid >> 2, ch = tid & 3;
            *(bf16x8*)&Qlds[r][ch*8] =
                *(const bf16x8*)&qh[((size_t)bh*MM + nn0 + r)*HD + ch*8];
        }
        __syncthreads();
        #pragma unroll
        for (int nt = 0; nt < 4; ++nt) {
            bf16x8 bf = *(const bf16x8*)&Qlds[nt*16 + (l&15)][(l>>4)<<3];
            f32x4 acc = {0.f,0.f,0.f,0.f};
            acc = __builtin_amdgcn_mfma_f32_16x16x32_bf16(af, bf, acc, 0, 0, 0);
            rs0 += __expf(acc[0]); rs1 += __expf(acc[1]);
            rs2 += __expf(acc[2]); rs3 += __expf(acc[3]);
        }
    }
    float rs[4] = {rs0, rs1, rs2, rs3};
    #pragma unroll
    for (int r = 0; r < 4; ++r) {
        float v = rs[r];
        v += __shfl_xor(v, 1, 64);
        v += __shfl_xor(v, 2, 64);
        v += __shfl_xor(v, 4, 64);
        v += __shfl_xor(v, 8, 64);
        if ((l & 15) == 0)
            denom[(size_t)bh*MM + mm0 + w*16 + ((l>>4)<<2) + r] = v;
    }
}

// K4c (MFMA): attnout[b][nn][h*32+d] = sum_mm exp(k_mm.q_nn)/denom[mm] * v[mm][d]
// block = (bh, 64-nn tile), 4 waves; wave w owns nn-subtile w for output.
__global__ void k4c_mfma(const u16* __restrict__ qh, const u16* __restrict__ kh,
                         const u16* __restrict__ vth, const float* __restrict__ denom,
                         float* __restrict__ attnout) {
    int bx = blockIdx.x;
    int bh = bx >> 5;
    int ntile = bx & 31;
    int nn0 = ntile * 64;
    int b = bh >> 3, h = bh & 7;
    int tid = threadIdx.x, w = tid >> 6, l = tid & 63;
    // Q-frags, loop-invariant (4 nn-subtiles)
    bf16x8 qf[4];
    #pragma unroll
    for (int nt = 0; nt < 4; ++nt)
        qf[nt] = *(const bf16x8*)&qh[((size_t)bh*MM + nn0 + nt*16 + (l&15))*HD + ((l>>4)<<3)];
    __shared__ u16 Klds[64][40];
    __shared__ u16 Vtlds[32][72];
    __shared__ u16 Wlds[64][72];
    __shared__ float Rlds[64];
    f32x4 o0 = {0.f,0.f,0.f,0.f}, o1 = {0.f,0.f,0.f,0.f};
    for (int mm0 = 0; mm0 < MM; mm0 += 64) {
        __syncthreads();
        {   // stage K-tile (64x32), Vt-tile (32x64), 1/denom (64)
            int r = tid >> 2, ch = tid & 3;
            *(bf16x8*)&Klds[r][ch*8] =
                *(const bf16x8*)&kh[((size_t)bh*MM + mm0 + r)*HD + ch*8];
            int d = tid >> 3, ch2 = tid & 7;
            *(bf16x8*)&Vtlds[d][ch2*8] =
                *(const bf16x8*)&vth[((size_t)bh*HD + d)*MM + mm0 + ch2*8];
            if (tid < 64) Rlds[tid] = 1.0f / denom[(size_t)bh*MM + mm0 + tid];
        }
        __syncthreads();
        // GEMM1: S[mm-sub w][all nn] ; W = exp(S)*rinv -> Wlds[nn][mm]
        {
            bf16x8 af = *(const bf16x8*)&Klds[w*16 + (l&15)][(l>>4)<<3];
            float rinv[4];
            #pragma unroll
            for (int r = 0; r < 4; ++r) rinv[r] = Rlds[w*16 + ((l>>4)<<2) + r];
            #pragma unroll
            for (int nt = 0; nt < 4; ++nt) {
                f32x4 s = {0.f,0.f,0.f,0.f};
                s = __builtin_amdgcn_mfma_f32_16x16x32_bf16(af, qf[nt], s, 0, 0, 0);
                unsigned p0 = (unsigned)f2bfu(__expf(s[0]) * rinv[0])
                            | ((unsigned)f2bfu(__expf(s[1]) * rinv[1]) << 16);
                unsigned p1 = (unsigned)f2bfu(__expf(s[2]) * rinv[2])
                            | ((unsigned)f2bfu(__expf(s[3]) * rinv[3]) << 16);
                uint2 pk; pk.x = p0; pk.y = p1;
                *(uint2*)&Wlds[nt*16 + (l&15)][w*16 + ((l>>4)<<2)] = pk;
            }
        }
        __syncthreads();
        // GEMM2: O[nn-sub w][32d] += W^T(nn x mm) * V(mm x d)
        #pragma unroll
        for (int ks = 0; ks < 2; ++ks) {
            bf16x8 a2 = *(const bf16x8*)&Wlds[w*16 + (l&15)][ks*32 + ((l>>4)<<3)];
            bf16x8 b20 = *(const bf16x8*)&Vtlds[(l&15)][ks*32 + ((l>>4)<<3)];
            bf16x8 b21 = *(const bf16x8*)&Vtlds[16 + (l&15)][ks*32 + ((l>>4)<<3)];
            o0 = __builtin_amdgcn_mfma_f32_16x16x32_bf16(a2, b20, o0, 0, 0, 0);
            o1 = __builtin_amdgcn_mfma_f32_16x16x32_bf16(a2, b21, o1, 0, 0, 0);
        }
    }
    // epilogue: rows nn = nn0 + w*16 + (l>>4)*4 + r ; col d = dt*16 + (l&15)
    int nnb = nn0 + w*16 + ((l>>4)<<2);
    int dcol = h*32 + (l&15);
    #pragma unroll
    for (int r = 0; r < 4; ++r) {
        attnout[((size_t)b*MM + nnb + r)*CC + dcol]      = o0[r];
        attnout[((size_t)b*MM + nnb + r)*CC + dcol + 16] = o1[r];
    }
}

// K5 (LDS-tiled): sf2r[b,o,mm] = Wproj @ attnout + bproj
__global__ void k5_proj(const float* __restrict__ attnout, const float* __restrict__ wproj,
                        const float* __restrict__ bproj, float* __restrict__ sf2r) {
    int blk = blockIdx.x; int b = blk / (MM/16), mt = blk % (MM/16);
    int mm0 = mt*16;
    __shared__ float al[16][CC+1];
    __shared__ float wl[16][CC+1];
    int tid = threadIdx.x;
    for (int idx = tid; idx < 16*CC; idx += 256) {
        int r = idx >> 8, c = idx & 255;
        al[r][c] = attnout[((size_t)b*MM + mm0 + r)*CC + c];
    }
    __syncthreads();
    int ml = tid & 15, og = tid >> 4;
    for (int ob = 0; ob < CC; ob += 16) {
        for (int idx = tid; idx < 16*CC; idx += 256) {
            int r = idx >> 8, c = idx & 255;
            wl[r][c] = wproj[(size_t)(ob + r)*CC + c];
        }
        __syncthreads();
        float acc = 0.f;
        for (int c = 0; c < CC; ++c) acc += wl[og][c]*al[ml][c];
        int o = ob + og;
        sf2r[((size_t)b*CC + o)*MM + mm0 + ml] = acc + bproj[o];
        __syncthreads();
    }
}

// K6: out[b,c,j*16+i] = sum_k sf2r[b,c,j+k-1]*aff[b,j,i,k]  (fp32 output)
__global__ void k6_final(const float* __restrict__ sf2r, const float* __restrict__ aff,
                         float* __restrict__ out) {
    int blk = blockIdx.x;
    int b = blk / (MM/16), jt = blk % (MM/16);
    int jb = jt*16;
    int tid = threadIdx.x;               // 256 tokens
    int jl = tid >> 4, il = tid & 15;
    int j = jb + jl;
    size_t abase = (((size_t)b*MM + j)*SN + il)*3;
    float a0 = aff[abase], a1 = aff[abase+1], a2 = aff[abase+2];
    __shared__ float stile[16][19];
    int t = jb*SN + tid;
    for (int ct = 0; ct < 16; ++ct) {
        for (int idx = tid; idx < 16*18; idx += 256) {
            int cl = idx / 18, jo = idx % 18;
            int jj = jb - 1 + jo;
            stile[cl][jo] = (jj >= 0 && jj < MM) ? sf2r[((size_t)b*CC + ct*16 + cl)*MM + jj] : 0.f;
        }
        __syncthreads();
        #pragma unroll
        for (int cl = 0; cl < 16; ++cl) {
            float v = stile[cl][jl]*a0 + stile[cl][jl+1]*a1 + stile[cl][jl+2]*a2;
            out[((size_t)b*CC + ct*16 + cl)*NN + t] = v;
        }
        __syncthreads();
    }
}

extern "C" void kernel_launch(void* const* d_in, const int* in_sizes, int n_in,
                              void* d_out, int out_size, void* d_ws, size_t ws_size,
                              hipStream_t stream) {
    const float *x = nullptr, *wqkv = nullptr, *wproj = nullptr, *bproj = nullptr;
    for (int i = 0; i < n_in; ++i) {
        int sz = in_sizes[i];
        if (sz == BB*NN*CC)        x     = (const float*)d_in[i];
        else if (sz == 3*CC*CC)    wqkv  = (const float*)d_in[i];
        else if (sz == CC*CC)      wproj = (const float*)d_in[i];
        else if (sz == CC)         bproj = (const float*)d_in[i];
    }
    float* out = (float*)d_out;    // reference output dtype is float32
    char* ws = (char*)d_ws;
    const size_t MB = 1024*1024;
    // Workspace (16.1 MiB total)
    float* aff     = (float*)(ws);            // 0.75 MiB (k2 -> k6)
    float* regA    = (float*)(ws + 1*MB);     // 4 MiB: sf (k1->k2), sf2 (k3->k4a), attnout (k4c->k5)
    u16*   qh      = (u16*)  (ws + 5*MB);     // 2 MiB bf16 [bh][m][32]
    u16*   kh      = (u16*)  (ws + 7*MB);     // 2 MiB bf16 [bh][m][32]
    u16*   vth     = (u16*)  (ws + 9*MB);     // 2 MiB bf16 [bh][32][m]
    float* denom   = (float*)(ws + 11*MB);    // 128 KiB
    float* sf2r    = (float*)(ws + 12*MB);    // 4 MiB (k5->k6)
    float* sf      = regA;
    float* sf2     = regA;
    float* attnout = regA;

    k1_sf   <<<BB*MM, 256, 0, stream>>>(x, sf);
    k2_aff  <<<BB*MM, 256, 0, stream>>>(x, sf, aff);
    k3_sf2  <<<BB*MM, 256, 0, stream>>>(x, aff, sf2);
    k4a_qkv <<<BB*(MM/16), 256, 0, stream>>>(sf2, wqkv, qh, kh, vth);
    k4b_mfma<<<BB*HH*(MM/64), 256, 0, stream>>>(qh, kh, denom);
    k4c_mfma<<<BB*HH*(MM/64), 256, 0, stream>>>(qh, kh, vth, denom, attnout);
    k5_proj <<<BB*(MM/16), 256, 0, stream>>>(attnout, wproj, bproj, sf2r);
    k6_final<<<BB*(MM/16), 256, 0, stream>>>(sf2r, aff, out);
}

// Round 6
// 172.260 us; speedup vs baseline: 16.7250x; 1.9590x over previous
//
#include <hip/hip_runtime.h>
#include <hip/hip_bf16.h>

#define BB 2
#define NN 32768
#define CC 256
#define SN 16
#define MM 2048          // NN/SN
#define HH 8
#define HD 32
#define QSCALE 0.17677669529663687f   // 1/sqrt(32)
#define AFFSCALE 0.0625f              // C^-0.5

typedef unsigned short u16;
typedef __attribute__((ext_vector_type(8))) short bf16x8;
typedef __attribute__((ext_vector_type(4))) float f32x4;
typedef __attribute__((ext_vector_type(4))) unsigned short u16x4;

// RNE float->bf16 bits
__device__ __forceinline__ u16 f2bfu(float x) {
    unsigned u = __float_as_uint(x);
    u = (u + 0x7fff + ((u >> 16) & 1)) >> 16;
    return (u16)u;
}

// K1: sf[b,j,c] = mean over 16 tokens
__global__ void k1_sf(const float* __restrict__ x, float* __restrict__ sf) {
    int blk = blockIdx.x;           // b*MM + j
    int b = blk / MM, j = blk % MM;
    int c = threadIdx.x;
    const float* xp = x + ((size_t)(b*NN + j*SN))*CC + c;
    float s = 0.f;
    #pragma unroll
    for (int i = 0; i < SN; ++i) s += xp[i*CC];
    sf[(size_t)blk*CC + c] = s * (1.0f/16.0f);
}

// K2: aff[b,j,i,k] = softmax_k( pix . sf[j+k-1] * scale ), OOB superpixel -> logit 0
__global__ void k2_aff(const float* __restrict__ x, const float* __restrict__ sf,
                       float* __restrict__ aff) {
    int blk = blockIdx.x; int b = blk / MM, j = blk % MM;
    __shared__ float sfl[3][CC];
    __shared__ float xl[SN][CC];
    int tid = threadIdx.x;
    #pragma unroll
    for (int k = 0; k < 3; ++k) {
        int w = j + k - 1;
        sfl[k][tid] = (w >= 0 && w < MM) ? sf[((size_t)b*MM + w)*CC + tid] : 0.f;
    }
    for (int i = 0; i < SN; ++i)
        xl[i][tid] = x[((size_t)(b*NN + j*SN + i))*CC + tid];
    __syncthreads();
    int wave = tid >> 6, lane = tid & 63;
    for (int qi = 0; qi < 4; ++qi) {
        int i = wave*4 + qi;
        float d0=0.f, d1=0.f, d2=0.f;
        #pragma unroll
        for (int cq = 0; cq < 4; ++cq) {
            int c = lane + cq*64;
            float xv = xl[i][c];
            d0 += xv * sfl[0][c];
            d1 += xv * sfl[1][c];
            d2 += xv * sfl[2][c];
        }
        #pragma unroll
        for (int off = 32; off >= 1; off >>= 1) {
            d0 += __shfl_xor(d0, off, 64);
            d1 += __shfl_xor(d1, off, 64);
            d2 += __shfl_xor(d2, off, 64);
        }
        if (lane == 0) {
            float l0 = d0*AFFSCALE, l1 = d1*AFFSCALE, l2 = d2*AFFSCALE;
            float mx = fmaxf(l0, fmaxf(l1, l2));
            float e0 = __expf(l0-mx), e1 = __expf(l1-mx), e2 = __expf(l2-mx);
            float inv = 1.0f/(e0+e1+e2);
            size_t base = ((size_t)blk*SN + i)*3;
            aff[base+0] = e0*inv; aff[base+1] = e1*inv; aff[base+2] = e2*inv;
        }
    }
}

// K3: sf2[b,j,c] = (fold of aff-weighted pixel sums) / (aff_sum + 1e-12)
__global__ void k3_sf2(const float* __restrict__ x, const float* __restrict__ aff,
                       float* __restrict__ sf2) {
    int blk = blockIdx.x; int b = blk / MM, j = blk % MM;
    int c = threadIdx.x;
    __shared__ float al[3][SN];
    __shared__ float asum_sh;
    if (threadIdx.x < 48) {
        int k = threadIdx.x / 16, i = threadIdx.x % 16;
        int w = (k == 0) ? j+1 : (k == 1) ? j : j-1;
        al[k][i] = (w >= 0 && w < MM) ? aff[(((size_t)b*MM + w)*SN + i)*3 + k] : 0.f;
    }
    __syncthreads();
    if (threadIdx.x == 0) {
        float s = 0.f;
        for (int t = 0; t < 48; ++t) s += al[t/16][t%16];
        asum_sh = s;
    }
    float acc = 0.f;
    #pragma unroll
    for (int k = 0; k < 3; ++k) {
        int w = (k==0)? j+1 : (k==1)? j : j-1;
        if (w < 0 || w >= MM) continue;
        const float* xp = x + ((size_t)(b*NN + w*SN))*CC + c;
        #pragma unroll
        for (int i = 0; i < SN; ++i) acc += xp[i*CC] * al[k][i];
    }
    __syncthreads();
    sf2[((size_t)b*MM + j)*CC + c] = acc / (asum_sh + 1e-12f);
}

// K4a (MFMA): qkv GEMM. Block = 64m x 64o tile, full K=256 in LDS (bf16).
// D[row=m][col=o]: A = sf2 rows (m), B = Wqkv rows (o).
__global__ void k4a_mfma(const float* __restrict__ sf2, const float* __restrict__ wqkv,
                         u16* __restrict__ qh, u16* __restrict__ kh, u16* __restrict__ vth) {
    int mt = blockIdx.x, ot = blockIdx.y, b = blockIdx.z;
    int mm0 = mt*64, oo0 = ot*64;
    __shared__ u16 S[64][264];
    __shared__ u16 W[64][264];
    int tid = threadIdx.x;
    for (int idx = tid; idx < 64*64; idx += 256) {
        int r = idx >> 6, c4 = (idx & 63) << 2;
        float4 sv = *(const float4*)&sf2[((size_t)b*MM + mm0 + r)*CC + c4];
        *(u16x4*)&S[r][c4] = (u16x4){f2bfu(sv.x), f2bfu(sv.y), f2bfu(sv.z), f2bfu(sv.w)};
        float4 wv = *(const float4*)&wqkv[(size_t)(oo0 + r)*CC + c4];
        *(u16x4*)&W[r][c4] = (u16x4){f2bfu(wv.x), f2bfu(wv.y), f2bfu(wv.z), f2bfu(wv.w)};
    }
    __syncthreads();
    int w = tid >> 6, l = tid & 63;
    f32x4 acc[4] = {{0.f,0.f,0.f,0.f},{0.f,0.f,0.f,0.f},{0.f,0.f,0.f,0.f},{0.f,0.f,0.f,0.f}};
    #pragma unroll
    for (int kc = 0; kc < 8; ++kc) {
        bf16x8 bf = *(const bf16x8*)&W[w*16 + (l&15)][kc*32 + ((l>>4)<<3)];
        #pragma unroll
        for (int nt = 0; nt < 4; ++nt) {
            bf16x8 af = *(const bf16x8*)&S[nt*16 + (l&15)][kc*32 + ((l>>4)<<3)];
            acc[nt] = __builtin_amdgcn_mfma_f32_16x16x32_bf16(af, bf, acc[nt], 0, 0, 0);
        }
    }
    // epilogue: o = oo0 + w*16 + (l&15); m = mm0 + nt*16 + (l>>4)*4 + r
    int o = oo0 + w*16 + (l&15);
    int h = o / 96, rr = o % 96;
    int bh = b*HH + h;
    int m0 = mm0 + ((l>>4)<<2);
    #pragma unroll
    for (int nt = 0; nt < 4; ++nt) {
        #pragma unroll
        for (int r = 0; r < 4; ++r) {
            int m = m0 + nt*16 + r;
            float v = acc[nt][r];
            if (rr < 32)      qh[((size_t)bh*MM + m)*HD + rr]       = f2bfu(v * QSCALE);
            else if (rr < 64) kh[((size_t)bh*MM + m)*HD + (rr-32)]  = f2bfu(v);
            else              vth[((size_t)bh*HD + (rr-64))*MM + m] = f2bfu(v);
        }
    }
}

// K4b (MFMA): denom[bh][mm] = sum over all nn of exp(k_mm . q_nn)
__global__ void k4b_mfma(const u16* __restrict__ qh, const u16* __restrict__ kh,
                         float* __restrict__ denom) {
    int bx = blockIdx.x;
    int bh = bx >> 5;                 // MM/64 = 32 tiles
    int mt = bx & 31;
    int mm0 = mt * 64;
    int tid = threadIdx.x, w = tid >> 6, l = tid & 63;
    bf16x8 af = *(const bf16x8*)&kh[((size_t)bh*MM + mm0 + w*16 + (l&15))*HD + ((l>>4)<<3)];
    __shared__ u16 Qlds[64][40];
    float rs0=0.f, rs1=0.f, rs2=0.f, rs3=0.f;
    for (int nn0 = 0; nn0 < MM; nn0 += 64) {
        __syncthreads();
        {
            int r = tid >> 2, ch = tid & 3;
            *(bf16x8*)&Qlds[r][ch*8] =
                *(const bf16x8*)&qh[((size_t)bh*MM + nn0 + r)*HD + ch*8];
        }
        __syncthreads();
        #pragma unroll
        for (int nt = 0; nt < 4; ++nt) {
            bf16x8 bf = *(const bf16x8*)&Qlds[nt*16 + (l&15)][(l>>4)<<3];
            f32x4 acc = {0.f,0.f,0.f,0.f};
            acc = __builtin_amdgcn_mfma_f32_16x16x32_bf16(af, bf, acc, 0, 0, 0);
            rs0 += __expf(acc[0]); rs1 += __expf(acc[1]);
            rs2 += __expf(acc[2]); rs3 += __expf(acc[3]);
        }
    }
    float rs[4] = {rs0, rs1, rs2, rs3};
    #pragma unroll
    for (int r = 0; r < 4; ++r) {
        float v = rs[r];
        v += __shfl_xor(v, 1, 64);
        v += __shfl_xor(v, 2, 64);
        v += __shfl_xor(v, 4, 64);
        v += __shfl_xor(v, 8, 64);
        if ((l & 15) == 0)
            denom[(size_t)bh*MM + mm0 + w*16 + ((l>>4)<<2) + r] = v;
    }
}

// K4c (MFMA): attnout[b][nn][h*32+d] = sum_mm exp(k_mm.q_nn)/denom[mm] * v[mm][d]
__global__ void k4c_mfma(const u16* __restrict__ qh, const u16* __restrict__ kh,
                         const u16* __restrict__ vth, const float* __restrict__ denom,
                         float* __restrict__ attnout) {
    int bx = blockIdx.x;
    int bh = bx >> 5;
    int ntile = bx & 31;
    int nn0 = ntile * 64;
    int b = bh >> 3, h = bh & 7;
    int tid = threadIdx.x, w = tid >> 6, l = tid & 63;
    bf16x8 qf[4];
    #pragma unroll
    for (int nt = 0; nt < 4; ++nt)
        qf[nt] = *(const bf16x8*)&qh[((size_t)bh*MM + nn0 + nt*16 + (l&15))*HD + ((l>>4)<<3)];
    __shared__ u16 Klds[64][40];
    __shared__ u16 Vtlds[32][72];
    __shared__ u16 Wlds[64][72];
    __shared__ float Rlds[64];
    f32x4 o0 = {0.f,0.f,0.f,0.f}, o1 = {0.f,0.f,0.f,0.f};
    for (int mm0 = 0; mm0 < MM; mm0 += 64) {
        __syncthreads();
        {
            int r = tid >> 2, ch = tid & 3;
            *(bf16x8*)&Klds[r][ch*8] =
                *(const bf16x8*)&kh[((size_t)bh*MM + mm0 + r)*HD + ch*8];
            int d = tid >> 3, ch2 = tid & 7;
            *(bf16x8*)&Vtlds[d][ch2*8] =
                *(const bf16x8*)&vth[((size_t)bh*HD + d)*MM + mm0 + ch2*8];
            if (tid < 64) Rlds[tid] = 1.0f / denom[(size_t)bh*MM + mm0 + tid];
        }
        __syncthreads();
        {
            bf16x8 af = *(const bf16x8*)&Klds[w*16 + (l&15)][(l>>4)<<3];
            float rinv[4];
            #pragma unroll
            for (int r = 0; r < 4; ++r) rinv[r] = Rlds[w*16 + ((l>>4)<<2) + r];
            #pragma unroll
            for (int nt = 0; nt < 4; ++nt) {
                f32x4 s = {0.f,0.f,0.f,0.f};
                s = __builtin_amdgcn_mfma_f32_16x16x32_bf16(af, qf[nt], s, 0, 0, 0);
                unsigned p0 = (unsigned)f2bfu(__expf(s[0]) * rinv[0])
                            | ((unsigned)f2bfu(__expf(s[1]) * rinv[1]) << 16);
                unsigned p1 = (unsigned)f2bfu(__expf(s[2]) * rinv[2])
                            | ((unsigned)f2bfu(__expf(s[3]) * rinv[3]) << 16);
                uint2 pk; pk.x = p0; pk.y = p1;
                *(uint2*)&Wlds[nt*16 + (l&15)][w*16 + ((l>>4)<<2)] = pk;
            }
        }
        __syncthreads();
        #pragma unroll
        for (int ks = 0; ks < 2; ++ks) {
            bf16x8 a2 = *(const bf16x8*)&Wlds[w*16 + (l&15)][ks*32 + ((l>>4)<<3)];
            bf16x8 b20 = *(const bf16x8*)&Vtlds[(l&15)][ks*32 + ((l>>4)<<3)];
            bf16x8 b21 = *(const bf16x8*)&Vtlds[16 + (l&15)][ks*32 + ((l>>4)<<3)];
            o0 = __builtin_amdgcn_mfma_f32_16x16x32_bf16(a2, b20, o0, 0, 0, 0);
            o1 = __builtin_amdgcn_mfma_f32_16x16x32_bf16(a2, b21, o1, 0, 0, 0);
        }
    }
    int nnb = nn0 + w*16 + ((l>>4)<<2);
    int dcol = h*32 + (l&15);
    #pragma unroll
    for (int r = 0; r < 4; ++r) {
        attnout[((size_t)b*MM + nnb + r)*CC + dcol]      = o0[r];
        attnout[((size_t)b*MM + nnb + r)*CC + dcol + 16] = o1[r];
    }
}

// K5 (MFMA): sf2r[b,o,m] = Wproj @ attnout + bproj. Block = 64m x 64o, K=256 in LDS.
__global__ void k5_mfma(const float* __restrict__ attnout, const float* __restrict__ wproj,
                        const float* __restrict__ bproj, float* __restrict__ sf2r) {
    int mt = blockIdx.x, ot = blockIdx.y, b = blockIdx.z;
    int mm0 = mt*64, oo0 = ot*64;
    __shared__ u16 S[64][264];
    __shared__ u16 W[64][264];
    int tid = threadIdx.x;
    for (int idx = tid; idx < 64*64; idx += 256) {
        int r = idx >> 6, c4 = (idx & 63) << 2;
        float4 sv = *(const float4*)&attnout[((size_t)b*MM + mm0 + r)*CC + c4];
        *(u16x4*)&S[r][c4] = (u16x4){f2bfu(sv.x), f2bfu(sv.y), f2bfu(sv.z), f2bfu(sv.w)};
        float4 wv = *(const float4*)&wproj[(size_t)(oo0 + r)*CC + c4];
        *(u16x4*)&W[r][c4] = (u16x4){f2bfu(wv.x), f2bfu(wv.y), f2bfu(wv.z), f2bfu(wv.w)};
    }
    __syncthreads();
    int w = tid >> 6, l = tid & 63;
    f32x4 acc[4] = {{0.f,0.f,0.f,0.f},{0.f,0.f,0.f,0.f},{0.f,0.f,0.f,0.f},{0.f,0.f,0.f,0.f}};
    #pragma unroll
    for (int kc = 0; kc < 8; ++kc) {
        bf16x8 bf = *(const bf16x8*)&W[w*16 + (l&15)][kc*32 + ((l>>4)<<3)];
        #pragma unroll
        for (int nt = 0; nt < 4; ++nt) {
            bf16x8 af = *(const bf16x8*)&S[nt*16 + (l&15)][kc*32 + ((l>>4)<<3)];
            acc[nt] = __builtin_amdgcn_mfma_f32_16x16x32_bf16(af, bf, acc[nt], 0, 0, 0);
        }
    }
    int o = oo0 + w*16 + (l&15);
    float bp = bproj[o];
    int m0 = mm0 + ((l>>4)<<2);
    #pragma unroll
    for (int nt = 0; nt < 4; ++nt) {
        #pragma unroll
        for (int r = 0; r < 4; ++r) {
            sf2r[((size_t)b*CC + o)*MM + m0 + nt*16 + r] = acc[nt][r] + bp;
        }
    }
}

// K6: out[b,c,j*16+i] = sum_k sf2r[b,c,j+k-1]*aff[b,j,i,k]  (fp32 output)
__global__ void k6_final(const float* __restrict__ sf2r, const float* __restrict__ aff,
                         float* __restrict__ out) {
    int blk = blockIdx.x;
    int b = blk / (MM/16), jt = blk % (MM/16);
    int jb = jt*16;
    int tid = threadIdx.x;               // 256 tokens
    int jl = tid >> 4, il = tid & 15;
    int j = jb + jl;
    size_t abase = (((size_t)b*MM + j)*SN + il)*3;
    float a0 = aff[abase], a1 = aff[abase+1], a2 = aff[abase+2];
    __shared__ float stile[16][19];
    int t = jb*SN + tid;
    for (int ct = 0; ct < 16; ++ct) {
        for (int idx = tid; idx < 16*18; idx += 256) {
            int cl = idx / 18, jo = idx % 18;
            int jj = jb - 1 + jo;
            stile[cl][jo] = (jj >= 0 && jj < MM) ? sf2r[((size_t)b*CC + ct*16 + cl)*MM + jj] : 0.f;
        }
        __syncthreads();
        #pragma unroll
        for (int cl = 0; cl < 16; ++cl) {
            float v = stile[cl][jl]*a0 + stile[cl][jl+1]*a1 + stile[cl][jl+2]*a2;
            out[((size_t)b*CC + ct*16 + cl)*NN + t] = v;
        }
        __syncthreads();
    }
}

extern "C" void kernel_launch(void* const* d_in, const int* in_sizes, int n_in,
                              void* d_out, int out_size, void* d_ws, size_t ws_size,
                              hipStream_t stream) {
    const float *x = nullptr, *wqkv = nullptr, *wproj = nullptr, *bproj = nullptr;
    for (int i = 0; i < n_in; ++i) {
        int sz = in_sizes[i];
        if (sz == BB*NN*CC)        x     = (const float*)d_in[i];
        else if (sz == 3*CC*CC)    wqkv  = (const float*)d_in[i];
        else if (sz == CC*CC)      wproj = (const float*)d_in[i];
        else if (sz == CC)         bproj = (const float*)d_in[i];
    }
    float* out = (float*)d_out;    // reference output dtype is float32
    char* ws = (char*)d_ws;
    const size_t MB = 1024*1024;
    // Workspace (16.1 MiB total)
    float* aff     = (float*)(ws);            // 0.75 MiB (k2 -> k6)
    float* regA    = (float*)(ws + 1*MB);     // 4 MiB: sf (k1->k2), sf2 (k3->k4a), attnout (k4c->k5)
    u16*   qh      = (u16*)  (ws + 5*MB);     // 2 MiB bf16 [bh][m][32]
    u16*   kh      = (u16*)  (ws + 7*MB);     // 2 MiB bf16 [bh][m][32]
    u16*   vth     = (u16*)  (ws + 9*MB);     // 2 MiB bf16 [bh][32][m]
    float* denom   = (float*)(ws + 11*MB);    // 128 KiB
    float* sf2r    = (float*)(ws + 12*MB);    // 4 MiB (k5->k6)
    float* sf      = regA;
    float* sf2     = regA;
    float* attnout = regA;

    k1_sf   <<<BB*MM, 256, 0, stream>>>(x, sf);
    k2_aff  <<<BB*MM, 256, 0, stream>>>(x, sf, aff);
    k3_sf2  <<<BB*MM, 256, 0, stream>>>(x, aff, sf2);
    k4a_mfma<<<dim3(MM/64, 12, BB), 256, 0, stream>>>(sf2, wqkv, qh, kh, vth);
    k4b_mfma<<<BB*HH*(MM/64), 256, 0, stream>>>(qh, kh, denom);
    k4c_mfma<<<BB*HH*(MM/64), 256, 0, stream>>>(qh, kh, vth, denom, attnout);
    k5_mfma <<<dim3(MM/64, 4, BB), 256, 0, stream>>>(attnout, wproj, bproj, sf2r);
    k6_final<<<BB*(MM/16), 256, 0, stream>>>(sf2r, aff, out);
}

// Round 7
// 156.514 us; speedup vs baseline: 18.4077x; 1.1006x over previous
//
#include <hip/hip_runtime.h>
#include <hip/hip_bf16.h>

#define BB 2
#define NN 32768
#define CC 256
#define SN 16
#define MM 2048          // NN/SN
#define HH 8
#define HD 32
#define PP1 4            // nn-partitions for denominator pass
#define PPB 4            // mm-partitions for output pass
#define QSCALE 0.17677669529663687f   // 1/sqrt(32)
#define AFFSCALE 0.0625f              // C^-0.5

typedef unsigned short u16;
typedef __attribute__((ext_vector_type(8))) short bf16x8;
typedef __attribute__((ext_vector_type(4))) float f32x4;
typedef __attribute__((ext_vector_type(4))) unsigned short u16x4;

// RNE float->bf16 bits
__device__ __forceinline__ u16 f2bfu(float x) {
    unsigned u = __float_as_uint(x);
    u = (u + 0x7fff + ((u >> 16) & 1)) >> 16;
    return (u16)u;
}

// K1: sf[b,j,c] = mean over 16 tokens
__global__ void k1_sf(const float* __restrict__ x, float* __restrict__ sf) {
    int blk = blockIdx.x;           // b*MM + j
    int b = blk / MM, j = blk % MM;
    int c = threadIdx.x;
    const float* xp = x + ((size_t)(b*NN + j*SN))*CC + c;
    float s = 0.f;
    #pragma unroll
    for (int i = 0; i < SN; ++i) s += xp[i*CC];
    sf[(size_t)blk*CC + c] = s * (1.0f/16.0f);
}

// K2: aff[b,j,i,k] = softmax_k( pix . sf[j+k-1] * scale ), OOB superpixel -> logit 0
__global__ void k2_aff(const float* __restrict__ x, const float* __restrict__ sf,
                       float* __restrict__ aff) {
    int blk = blockIdx.x; int b = blk / MM, j = blk % MM;
    __shared__ float sfl[3][CC];
    __shared__ float xl[SN][CC];
    int tid = threadIdx.x;
    #pragma unroll
    for (int k = 0; k < 3; ++k) {
        int w = j + k - 1;
        sfl[k][tid] = (w >= 0 && w < MM) ? sf[((size_t)b*MM + w)*CC + tid] : 0.f;
    }
    for (int i = 0; i < SN; ++i)
        xl[i][tid] = x[((size_t)(b*NN + j*SN + i))*CC + tid];
    __syncthreads();
    int wave = tid >> 6, lane = tid & 63;
    for (int qi = 0; qi < 4; ++qi) {
        int i = wave*4 + qi;
        float d0=0.f, d1=0.f, d2=0.f;
        #pragma unroll
        for (int cq = 0; cq < 4; ++cq) {
            int c = lane + cq*64;
            float xv = xl[i][c];
            d0 += xv * sfl[0][c];
            d1 += xv * sfl[1][c];
            d2 += xv * sfl[2][c];
        }
        #pragma unroll
        for (int off = 32; off >= 1; off >>= 1) {
            d0 += __shfl_xor(d0, off, 64);
            d1 += __shfl_xor(d1, off, 64);
            d2 += __shfl_xor(d2, off, 64);
        }
        if (lane == 0) {
            float l0 = d0*AFFSCALE, l1 = d1*AFFSCALE, l2 = d2*AFFSCALE;
            float mx = fmaxf(l0, fmaxf(l1, l2));
            float e0 = __expf(l0-mx), e1 = __expf(l1-mx), e2 = __expf(l2-mx);
            float inv = 1.0f/(e0+e1+e2);
            size_t base = ((size_t)blk*SN + i)*3;
            aff[base+0] = e0*inv; aff[base+1] = e1*inv; aff[base+2] = e2*inv;
        }
    }
}

// K3: sf2[b,j,c] = (fold of aff-weighted pixel sums) / (aff_sum + 1e-12)
__global__ void k3_sf2(const float* __restrict__ x, const float* __restrict__ aff,
                       float* __restrict__ sf2) {
    int blk = blockIdx.x; int b = blk / MM, j = blk % MM;
    int c = threadIdx.x;
    __shared__ float al[3][SN];
    __shared__ float asum_sh;
    if (threadIdx.x < 48) {
        int k = threadIdx.x / 16, i = threadIdx.x % 16;
        int w = (k == 0) ? j+1 : (k == 1) ? j : j-1;
        al[k][i] = (w >= 0 && w < MM) ? aff[(((size_t)b*MM + w)*SN + i)*3 + k] : 0.f;
    }
    __syncthreads();
    if (threadIdx.x == 0) {
        float s = 0.f;
        for (int t = 0; t < 48; ++t) s += al[t/16][t%16];
        asum_sh = s;
    }
    float acc = 0.f;
    #pragma unroll
    for (int k = 0; k < 3; ++k) {
        int w = (k==0)? j+1 : (k==1)? j : j-1;
        if (w < 0 || w >= MM) continue;
        const float* xp = x + ((size_t)(b*NN + w*SN))*CC + c;
        #pragma unroll
        for (int i = 0; i < SN; ++i) acc += xp[i*CC] * al[k][i];
    }
    __syncthreads();
    sf2[((size_t)b*MM + j)*CC + c] = acc / (asum_sh + 1e-12f);
}

// K4a (MFMA): qkv GEMM. Block = 64m x 64o tile, full K=256 in LDS (bf16).
__global__ void k4a_mfma(const float* __restrict__ sf2, const float* __restrict__ wqkv,
                         u16* __restrict__ qh, u16* __restrict__ kh, u16* __restrict__ vth) {
    int mt = blockIdx.x, ot = blockIdx.y, b = blockIdx.z;
    int mm0 = mt*64, oo0 = ot*64;
    __shared__ u16 S[64][264];
    __shared__ u16 W[64][264];
    int tid = threadIdx.x;
    for (int idx = tid; idx < 64*64; idx += 256) {
        int r = idx >> 6, c4 = (idx & 63) << 2;
        float4 sv = *(const float4*)&sf2[((size_t)b*MM + mm0 + r)*CC + c4];
        *(u16x4*)&S[r][c4] = (u16x4){f2bfu(sv.x), f2bfu(sv.y), f2bfu(sv.z), f2bfu(sv.w)};
        float4 wv = *(const float4*)&wqkv[(size_t)(oo0 + r)*CC + c4];
        *(u16x4*)&W[r][c4] = (u16x4){f2bfu(wv.x), f2bfu(wv.y), f2bfu(wv.z), f2bfu(wv.w)};
    }
    __syncthreads();
    int w = tid >> 6, l = tid & 63;
    f32x4 acc[4] = {{0.f,0.f,0.f,0.f},{0.f,0.f,0.f,0.f},{0.f,0.f,0.f,0.f},{0.f,0.f,0.f,0.f}};
    #pragma unroll
    for (int kc = 0; kc < 8; ++kc) {
        bf16x8 bf = *(const bf16x8*)&W[w*16 + (l&15)][kc*32 + ((l>>4)<<3)];
        #pragma unroll
        for (int nt = 0; nt < 4; ++nt) {
            bf16x8 af = *(const bf16x8*)&S[nt*16 + (l&15)][kc*32 + ((l>>4)<<3)];
            acc[nt] = __builtin_amdgcn_mfma_f32_16x16x32_bf16(af, bf, acc[nt], 0, 0, 0);
        }
    }
    int o = oo0 + w*16 + (l&15);
    int h = o / 96, rr = o % 96;
    int bh = b*HH + h;
    int m0 = mm0 + ((l>>4)<<2);
    #pragma unroll
    for (int nt = 0; nt < 4; ++nt) {
        #pragma unroll
        for (int r = 0; r < 4; ++r) {
            int m = m0 + nt*16 + r;
            float v = acc[nt][r];
            if (rr < 32)      qh[((size_t)bh*MM + m)*HD + rr]       = f2bfu(v * QSCALE);
            else if (rr < 64) kh[((size_t)bh*MM + m)*HD + (rr-32)]  = f2bfu(v);
            else              vth[((size_t)bh*HD + (rr-64))*MM + m] = f2bfu(v);
        }
    }
}

// K4b (MFMA, nn-partitioned): ses[p][bh][mm] = sum over nn-partition of exp(k_mm . q_nn)
__global__ void k4b_mfma(const u16* __restrict__ qh, const u16* __restrict__ kh,
                         float* __restrict__ ses) {
    int bx = blockIdx.x;
    int p = blockIdx.y;
    int bh = bx >> 5;                 // MM/64 = 32 tiles
    int mt = bx & 31;
    int mm0 = mt * 64;
    int tid = threadIdx.x, w = tid >> 6, l = tid & 63;
    bf16x8 af = *(const bf16x8*)&kh[((size_t)bh*MM + mm0 + w*16 + (l&15))*HD + ((l>>4)<<3)];
    __shared__ u16 Qlds[64][40];
    float rs0=0.f, rs1=0.f, rs2=0.f, rs3=0.f;
    int nnbeg = p * (MM/PP1), nnend = nnbeg + (MM/PP1);
    for (int nn0 = nnbeg; nn0 < nnend; nn0 += 64) {
        __syncthreads();
        {
            int r = tid >> 2, ch = tid & 3;
            *(bf16x8*)&Qlds[r][ch*8] =
                *(const bf16x8*)&qh[((size_t)bh*MM + nn0 + r)*HD + ch*8];
        }
        __syncthreads();
        #pragma unroll
        for (int nt = 0; nt < 4; ++nt) {
            bf16x8 bf = *(const bf16x8*)&Qlds[nt*16 + (l&15)][(l>>4)<<3];
            f32x4 acc = {0.f,0.f,0.f,0.f};
            acc = __builtin_amdgcn_mfma_f32_16x16x32_bf16(af, bf, acc, 0, 0, 0);
            rs0 += __expf(acc[0]); rs1 += __expf(acc[1]);
            rs2 += __expf(acc[2]); rs3 += __expf(acc[3]);
        }
    }
    float rs[4] = {rs0, rs1, rs2, rs3};
    #pragma unroll
    for (int r = 0; r < 4; ++r) {
        float v = rs[r];
        v += __shfl_xor(v, 1, 64);
        v += __shfl_xor(v, 2, 64);
        v += __shfl_xor(v, 4, 64);
        v += __shfl_xor(v, 8, 64);
        if ((l & 15) == 0)
            ses[((size_t)p*BB*HH + bh)*MM + mm0 + w*16 + ((l>>4)<<2) + r] = v;
    }
}

// K4bm: merge partial denominators -> rinv = 1/sum
__global__ void k4bm(const float* __restrict__ ses, float* __restrict__ rinv) {
    int e = blockIdx.x*256 + threadIdx.x;
    float s = 0.f;
    #pragma unroll
    for (int p = 0; p < PP1; ++p) s += ses[(size_t)p*(BB*HH*MM) + e];
    rinv[e] = 1.0f / s;
}

// K4c (MFMA, mm-partitioned): part[p][b][nn][h*32+d] = sum over mm-partition of
//   exp(k_mm.q_nn)*rinv[mm] * v[mm][d]
__global__ void k4c_mfma(const u16* __restrict__ qh, const u16* __restrict__ kh,
                         const u16* __restrict__ vth, const float* __restrict__ rinv,
                         float* __restrict__ part) {
    int bx = blockIdx.x;
    int p = blockIdx.y;
    int bh = bx >> 5;
    int ntile = bx & 31;
    int nn0 = ntile * 64;
    int b = bh >> 3, h = bh & 7;
    int tid = threadIdx.x, w = tid >> 6, l = tid & 63;
    bf16x8 qf[4];
    #pragma unroll
    for (int nt = 0; nt < 4; ++nt)
        qf[nt] = *(const bf16x8*)&qh[((size_t)bh*MM + nn0 + nt*16 + (l&15))*HD + ((l>>4)<<3)];
    __shared__ u16 Klds[64][40];
    __shared__ u16 Vtlds[32][72];
    __shared__ u16 Wlds[64][72];
    __shared__ float Rlds[64];
    f32x4 o0 = {0.f,0.f,0.f,0.f}, o1 = {0.f,0.f,0.f,0.f};
    int mmbeg = p * (MM/PPB), mmend = mmbeg + (MM/PPB);
    for (int mm0 = mmbeg; mm0 < mmend; mm0 += 64) {
        __syncthreads();
        {
            int r = tid >> 2, ch = tid & 3;
            *(bf16x8*)&Klds[r][ch*8] =
                *(const bf16x8*)&kh[((size_t)bh*MM + mm0 + r)*HD + ch*8];
            int d = tid >> 3, ch2 = tid & 7;
            *(bf16x8*)&Vtlds[d][ch2*8] =
                *(const bf16x8*)&vth[((size_t)bh*HD + d)*MM + mm0 + ch2*8];
            if (tid < 64) Rlds[tid] = rinv[(size_t)bh*MM + mm0 + tid];
        }
        __syncthreads();
        {
            bf16x8 af = *(const bf16x8*)&Klds[w*16 + (l&15)][(l>>4)<<3];
            float ri[4];
            #pragma unroll
            for (int r = 0; r < 4; ++r) ri[r] = Rlds[w*16 + ((l>>4)<<2) + r];
            #pragma unroll
            for (int nt = 0; nt < 4; ++nt) {
                f32x4 s = {0.f,0.f,0.f,0.f};
                s = __builtin_amdgcn_mfma_f32_16x16x32_bf16(af, qf[nt], s, 0, 0, 0);
                unsigned p0 = (unsigned)f2bfu(__expf(s[0]) * ri[0])
                            | ((unsigned)f2bfu(__expf(s[1]) * ri[1]) << 16);
                unsigned p1 = (unsigned)f2bfu(__expf(s[2]) * ri[2])
                            | ((unsigned)f2bfu(__expf(s[3]) * ri[3]) << 16);
                uint2 pk; pk.x = p0; pk.y = p1;
                *(uint2*)&Wlds[nt*16 + (l&15)][w*16 + ((l>>4)<<2)] = pk;
            }
        }
        __syncthreads();
        #pragma unroll
        for (int ks = 0; ks < 2; ++ks) {
            bf16x8 a2 = *(const bf16x8*)&Wlds[w*16 + (l&15)][ks*32 + ((l>>4)<<3)];
            bf16x8 b20 = *(const bf16x8*)&Vtlds[(l&15)][ks*32 + ((l>>4)<<3)];
            bf16x8 b21 = *(const bf16x8*)&Vtlds[16 + (l&15)][ks*32 + ((l>>4)<<3)];
            o0 = __builtin_amdgcn_mfma_f32_16x16x32_bf16(a2, b20, o0, 0, 0, 0);
            o1 = __builtin_amdgcn_mfma_f32_16x16x32_bf16(a2, b21, o1, 0, 0, 0);
        }
    }
    int nnb = nn0 + w*16 + ((l>>4)<<2);
    int dcol = h*32 + (l&15);
    float* op = part + ((size_t)p*BB + b)*((size_t)MM*CC);
    #pragma unroll
    for (int r = 0; r < 4; ++r) {
        op[((size_t)nnb + r)*CC + dcol]      = o0[r];
        op[((size_t)nnb + r)*CC + dcol + 16] = o1[r];
    }
}

// K4d: reduce partials -> attnout (B,M,C)
__global__ void k4d_red(const float* __restrict__ part, float* __restrict__ attnout) {
    size_t e = (size_t)blockIdx.x*256 + threadIdx.x;
    float s = 0.f;
    #pragma unroll
    for (int p = 0; p < PPB; ++p) s += part[(size_t)p*((size_t)BB*MM*CC) + e];
    attnout[e] = s;
}

// K5 (MFMA): sf2r[b,o,m] = Wproj @ attnout + bproj. Block = 64m x 64o, K=256 in LDS.
__global__ void k5_mfma(const float* __restrict__ attnout, const float* __restrict__ wproj,
                        const float* __restrict__ bproj, float* __restrict__ sf2r) {
    int mt = blockIdx.x, ot = blockIdx.y, b = blockIdx.z;
    int mm0 = mt*64, oo0 = ot*64;
    __shared__ u16 S[64][264];
    __shared__ u16 W[64][264];
    int tid = threadIdx.x;
    for (int idx = tid; idx < 64*64; idx += 256) {
        int r = idx >> 6, c4 = (idx & 63) << 2;
        float4 sv = *(const float4*)&attnout[((size_t)b*MM + mm0 + r)*CC + c4];
        *(u16x4*)&S[r][c4] = (u16x4){f2bfu(sv.x), f2bfu(sv.y), f2bfu(sv.z), f2bfu(sv.w)};
        float4 wv = *(const float4*)&wproj[(size_t)(oo0 + r)*CC + c4];
        *(u16x4*)&W[r][c4] = (u16x4){f2bfu(wv.x), f2bfu(wv.y), f2bfu(wv.z), f2bfu(wv.w)};
    }
    __syncthreads();
    int w = tid >> 6, l = tid & 63;
    f32x4 acc[4] = {{0.f,0.f,0.f,0.f},{0.f,0.f,0.f,0.f},{0.f,0.f,0.f,0.f},{0.f,0.f,0.f,0.f}};
    #pragma unroll
    for (int kc = 0; kc < 8; ++kc) {
        bf16x8 bf = *(const bf16x8*)&W[w*16 + (l&15)][kc*32 + ((l>>4)<<3)];
        #pragma unroll
        for (int nt = 0; nt < 4; ++nt) {
            bf16x8 af = *(const bf16x8*)&S[nt*16 + (l&15)][kc*32 + ((l>>4)<<3)];
            acc[nt] = __builtin_amdgcn_mfma_f32_16x16x32_bf16(af, bf, acc[nt], 0, 0, 0);
        }
    }
    int o = oo0 + w*16 + (l&15);
    float bp = bproj[o];
    int m0 = mm0 + ((l>>4)<<2);
    #pragma unroll
    for (int nt = 0; nt < 4; ++nt) {
        #pragma unroll
        for (int r = 0; r < 4; ++r) {
            sf2r[((size_t)b*CC + o)*MM + m0 + nt*16 + r] = acc[nt][r] + bp;
        }
    }
}

// K6: out[b,c,j*16+i] = sum_k sf2r[b,c,j+k-1]*aff[b,j,i,k]  (fp32 output)
__global__ void k6_final(const float* __restrict__ sf2r, const float* __restrict__ aff,
                         float* __restrict__ out) {
    int blk = blockIdx.x;
    int b = blk / (MM/16), jt = blk % (MM/16);
    int jb = jt*16;
    int tid = threadIdx.x;               // 256 tokens
    int jl = tid >> 4, il = tid & 15;
    int j = jb + jl;
    size_t abase = (((size_t)b*MM + j)*SN + il)*3;
    float a0 = aff[abase], a1 = aff[abase+1], a2 = aff[abase+2];
    __shared__ float stile[16][19];
    int t = jb*SN + tid;
    for (int ct = 0; ct < 16; ++ct) {
        for (int idx = tid; idx < 16*18; idx += 256) {
            int cl = idx / 18, jo = idx % 18;
            int jj = jb - 1 + jo;
            stile[cl][jo] = (jj >= 0 && jj < MM) ? sf2r[((size_t)b*CC + ct*16 + cl)*MM + jj] : 0.f;
        }
        __syncthreads();
        #pragma unroll
        for (int cl = 0; cl < 16; ++cl) {
            float v = stile[cl][jl]*a0 + stile[cl][jl+1]*a1 + stile[cl][jl+2]*a2;
            out[((size_t)b*CC + ct*16 + cl)*NN + t] = v;
        }
        __syncthreads();
    }
}

extern "C" void kernel_launch(void* const* d_in, const int* in_sizes, int n_in,
                              void* d_out, int out_size, void* d_ws, size_t ws_size,
                              hipStream_t stream) {
    const float *x = nullptr, *wqkv = nullptr, *wproj = nullptr, *bproj = nullptr;
    for (int i = 0; i < n_in; ++i) {
        int sz = in_sizes[i];
        if (sz == BB*NN*CC)        x     = (const float*)d_in[i];
        else if (sz == 3*CC*CC)    wqkv  = (const float*)d_in[i];
        else if (sz == CC*CC)      wproj = (const float*)d_in[i];
        else if (sz == CC)         bproj = (const float*)d_in[i];
    }
    float* out = (float*)d_out;    // reference output dtype is float32
    char* ws = (char*)d_ws;
    const size_t MB = 1024*1024;
    // Workspace (32 MiB total)
    float* aff     = (float*)(ws);            // 0.75 MiB (k2 -> k6)
    float* regA    = (float*)(ws + 1*MB);     // 4 MiB: sf (k1->k2), sf2 (k3->k4a), attnout (k4d->k5)
    u16*   qh      = (u16*)  (ws + 5*MB);     // 2 MiB bf16 [bh][m][32]
    u16*   kh      = (u16*)  (ws + 7*MB);     // 2 MiB bf16 [bh][m][32]
    u16*   vth     = (u16*)  (ws + 9*MB);     // 2 MiB bf16 [bh][32][m]
    float* ses     = (float*)(ws + 11*MB);    // 0.5 MiB (PP1 partials)
    float* rinv    = (float*)(ws + 11*MB + 512*1024);  // 128 KiB
    float* sf2r    = (float*)(ws + 12*MB);    // 4 MiB (k5->k6)
    float* part    = (float*)(ws + 16*MB);    // 16 MiB (PPB partials)
    float* sf      = regA;
    float* sf2     = regA;
    float* attnout = regA;

    k1_sf   <<<BB*MM, 256, 0, stream>>>(x, sf);
    k2_aff  <<<BB*MM, 256, 0, stream>>>(x, sf, aff);
    k3_sf2  <<<BB*MM, 256, 0, stream>>>(x, aff, sf2);
    k4a_mfma<<<dim3(MM/64, 12, BB), 256, 0, stream>>>(sf2, wqkv, qh, kh, vth);
    k4b_mfma<<<dim3(BB*HH*(MM/64), PP1), 256, 0, stream>>>(qh, kh, ses);
    k4bm    <<<(BB*HH*MM)/256, 256, 0, stream>>>(ses, rinv);
    k4c_mfma<<<dim3(BB*HH*(MM/64), PPB), 256, 0, stream>>>(qh, kh, vth, rinv, part);
    k4d_red <<<(int)(((size_t)BB*MM*CC)/256), 256, 0, stream>>>(part, attnout);
    k5_mfma <<<dim3(MM/64, 4, BB), 256, 0, stream>>>(attnout, wproj, bproj, sf2r);
    k6_final<<<BB*(MM/16), 256, 0, stream>>>(sf2r, aff, out);
}

// Round 8
// 143.537 us; speedup vs baseline: 20.0719x; 1.0904x over previous
//
#include <hip/hip_runtime.h>
#include <hip/hip_bf16.h>

#define BB 2
#define NN 32768
#define CC 256
#define SN 16
#define MM 2048          // NN/SN
#define HH 8
#define HD 32
#define PP1 4            // nn-partitions for denominator pass
#define PPB 4            // mm-partitions for output pass
#define QSCALE 0.17677669529663687f   // 1/sqrt(32)
#define AFFSCALE 0.0625f              // C^-0.5

typedef unsigned short u16;
typedef __attribute__((ext_vector_type(8))) short bf16x8;
typedef __attribute__((ext_vector_type(4))) float f32x4;
typedef __attribute__((ext_vector_type(4))) unsigned short u16x4;

// RNE float->bf16 bits
__device__ __forceinline__ u16 f2bfu(float x) {
    unsigned u = __float_as_uint(x);
    u = (u + 0x7fff + ((u >> 16) & 1)) >> 16;
    return (u16)u;
}

// K1: sf[b,j,c] = mean over 16 tokens
__global__ void k1_sf(const float* __restrict__ x, float* __restrict__ sf) {
    int blk = blockIdx.x;           // b*MM + j
    int b = blk / MM, j = blk % MM;
    int c = threadIdx.x;
    const float* xp = x + ((size_t)(b*NN + j*SN))*CC + c;
    float s = 0.f;
    #pragma unroll
    for (int i = 0; i < SN; ++i) s += xp[i*CC];
    sf[(size_t)blk*CC + c] = s * (1.0f/16.0f);
}

// K2: aff[b,j,i,k] = softmax_k( pix . sf[j+k-1] * scale ), OOB superpixel -> logit 0
__global__ void k2_aff(const float* __restrict__ x, const float* __restrict__ sf,
                       float* __restrict__ aff) {
    int blk = blockIdx.x; int b = blk / MM, j = blk % MM;
    __shared__ float sfl[3][CC];
    __shared__ float xl[SN][CC];
    int tid = threadIdx.x;
    #pragma unroll
    for (int k = 0; k < 3; ++k) {
        int w = j + k - 1;
        sfl[k][tid] = (w >= 0 && w < MM) ? sf[((size_t)b*MM + w)*CC + tid] : 0.f;
    }
    for (int idx = tid; idx < SN*64; idx += 256) {
        int i = idx >> 6, c4 = (idx & 63) << 2;
        *(float4*)&xl[i][c4] = *(const float4*)&x[((size_t)(b*NN + j*SN + i))*CC + c4];
    }
    __syncthreads();
    int wave = tid >> 6, lane = tid & 63;
    for (int qi = 0; qi < 4; ++qi) {
        int i = wave*4 + qi;
        float d0=0.f, d1=0.f, d2=0.f;
        #pragma unroll
        for (int cq = 0; cq < 4; ++cq) {
            int c = lane + cq*64;
            float xv = xl[i][c];
            d0 += xv * sfl[0][c];
            d1 += xv * sfl[1][c];
            d2 += xv * sfl[2][c];
        }
        #pragma unroll
        for (int off = 32; off >= 1; off >>= 1) {
            d0 += __shfl_xor(d0, off, 64);
            d1 += __shfl_xor(d1, off, 64);
            d2 += __shfl_xor(d2, off, 64);
        }
        if (lane == 0) {
            float l0 = d0*AFFSCALE, l1 = d1*AFFSCALE, l2 = d2*AFFSCALE;
            float mx = fmaxf(l0, fmaxf(l1, l2));
            float e0 = __expf(l0-mx), e1 = __expf(l1-mx), e2 = __expf(l2-mx);
            float inv = 1.0f/(e0+e1+e2);
            size_t base = ((size_t)blk*SN + i)*3;
            aff[base+0] = e0*inv; aff[base+1] = e1*inv; aff[base+2] = e2*inv;
        }
    }
}

// K3: sf2[b,j,c] = (fold of aff-weighted pixel sums) / (aff_sum + 1e-12)
__global__ void k3_sf2(const float* __restrict__ x, const float* __restrict__ aff,
                       float* __restrict__ sf2) {
    int blk = blockIdx.x; int b = blk / MM, j = blk % MM;
    int c = threadIdx.x;
    __shared__ float al[3][SN];
    __shared__ float asum_sh;
    if (threadIdx.x < 48) {
        int k = threadIdx.x / 16, i = threadIdx.x % 16;
        int w = (k == 0) ? j+1 : (k == 1) ? j : j-1;
        al[k][i] = (w >= 0 && w < MM) ? aff[(((size_t)b*MM + w)*SN + i)*3 + k] : 0.f;
    }
    __syncthreads();
    if (threadIdx.x == 0) {
        float s = 0.f;
        for (int t = 0; t < 48; ++t) s += al[t/16][t%16];
        asum_sh = s;
    }
    float acc = 0.f;
    #pragma unroll
    for (int k = 0; k < 3; ++k) {
        int w = (k==0)? j+1 : (k==1)? j : j-1;
        if (w < 0 || w >= MM) continue;
        const float* xp = x + ((size_t)(b*NN + w*SN))*CC + c;
        #pragma unroll
        for (int i = 0; i < SN; ++i) acc += xp[i*CC] * al[k][i];
    }
    __syncthreads();
    sf2[((size_t)b*MM + j)*CC + c] = acc / (asum_sh + 1e-12f);
}

// K4a (MFMA): qkv GEMM. Block = 64m x 64o tile, full K=256 in LDS (bf16).
__global__ void k4a_mfma(const float* __restrict__ sf2, const float* __restrict__ wqkv,
                         u16* __restrict__ qh, u16* __restrict__ kh, u16* __restrict__ vth) {
    int mt = blockIdx.x, ot = blockIdx.y, b = blockIdx.z;
    int mm0 = mt*64, oo0 = ot*64;
    __shared__ u16 S[64][264];
    __shared__ u16 W[64][264];
    int tid = threadIdx.x;
    for (int idx = tid; idx < 64*64; idx += 256) {
        int r = idx >> 6, c4 = (idx & 63) << 2;
        float4 sv = *(const float4*)&sf2[((size_t)b*MM + mm0 + r)*CC + c4];
        *(u16x4*)&S[r][c4] = (u16x4){f2bfu(sv.x), f2bfu(sv.y), f2bfu(sv.z), f2bfu(sv.w)};
        float4 wv = *(const float4*)&wqkv[(size_t)(oo0 + r)*CC + c4];
        *(u16x4*)&W[r][c4] = (u16x4){f2bfu(wv.x), f2bfu(wv.y), f2bfu(wv.z), f2bfu(wv.w)};
    }
    __syncthreads();
    int w = tid >> 6, l = tid & 63;
    f32x4 acc[4] = {{0.f,0.f,0.f,0.f},{0.f,0.f,0.f,0.f},{0.f,0.f,0.f,0.f},{0.f,0.f,0.f,0.f}};
    #pragma unroll
    for (int kc = 0; kc < 8; ++kc) {
        bf16x8 bf = *(const bf16x8*)&W[w*16 + (l&15)][kc*32 + ((l>>4)<<3)];
        #pragma unroll
        for (int nt = 0; nt < 4; ++nt) {
            bf16x8 af = *(const bf16x8*)&S[nt*16 + (l&15)][kc*32 + ((l>>4)<<3)];
            acc[nt] = __builtin_amdgcn_mfma_f32_16x16x32_bf16(af, bf, acc[nt], 0, 0, 0);
        }
    }
    int o = oo0 + w*16 + (l&15);
    int h = o / 96, rr = o % 96;
    int bh = b*HH + h;
    int m0 = mm0 + ((l>>4)<<2);
    #pragma unroll
    for (int nt = 0; nt < 4; ++nt) {
        #pragma unroll
        for (int r = 0; r < 4; ++r) {
            int m = m0 + nt*16 + r;
            float v = acc[nt][r];
            if (rr < 32)      qh[((size_t)bh*MM + m)*HD + rr]       = f2bfu(v * QSCALE);
            else if (rr < 64) kh[((size_t)bh*MM + m)*HD + (rr-32)]  = f2bfu(v);
            else              vth[((size_t)bh*HD + (rr-64))*MM + m] = f2bfu(v);
        }
    }
}

// K4b (MFMA, nn-partitioned): ses[p][bh][mm] = sum over nn-partition of exp(k_mm . q_nn)
__global__ void k4b_mfma(const u16* __restrict__ qh, const u16* __restrict__ kh,
                         float* __restrict__ ses) {
    int bx = blockIdx.x;
    int p = blockIdx.y;
    int bh = bx >> 5;                 // MM/64 = 32 tiles
    int mt = bx & 31;
    int mm0 = mt * 64;
    int tid = threadIdx.x, w = tid >> 6, l = tid & 63;
    bf16x8 af = *(const bf16x8*)&kh[((size_t)bh*MM + mm0 + w*16 + (l&15))*HD + ((l>>4)<<3)];
    __shared__ u16 Qlds[64][40];
    float rs0=0.f, rs1=0.f, rs2=0.f, rs3=0.f;
    int nnbeg = p * (MM/PP1), nnend = nnbeg + (MM/PP1);
    for (int nn0 = nnbeg; nn0 < nnend; nn0 += 64) {
        __syncthreads();
        {
            int r = tid >> 2, ch = tid & 3;
            *(bf16x8*)&Qlds[r][ch*8] =
                *(const bf16x8*)&qh[((size_t)bh*MM + nn0 + r)*HD + ch*8];
        }
        __syncthreads();
        #pragma unroll
        for (int nt = 0; nt < 4; ++nt) {
            bf16x8 bf = *(const bf16x8*)&Qlds[nt*16 + (l&15)][(l>>4)<<3];
            f32x4 acc = {0.f,0.f,0.f,0.f};
            acc = __builtin_amdgcn_mfma_f32_16x16x32_bf16(af, bf, acc, 0, 0, 0);
            rs0 += __expf(acc[0]); rs1 += __expf(acc[1]);
            rs2 += __expf(acc[2]); rs3 += __expf(acc[3]);
        }
    }
    float rs[4] = {rs0, rs1, rs2, rs3};
    #pragma unroll
    for (int r = 0; r < 4; ++r) {
        float v = rs[r];
        v += __shfl_xor(v, 1, 64);
        v += __shfl_xor(v, 2, 64);
        v += __shfl_xor(v, 4, 64);
        v += __shfl_xor(v, 8, 64);
        if ((l & 15) == 0)
            ses[((size_t)p*BB*HH + bh)*MM + mm0 + w*16 + ((l>>4)<<2) + r] = v;
    }
}

// K4c (MFMA, mm-partitioned, fused denominator merge):
//   part[p][b][nn][h*32+d] = sum over mm-partition of exp(k_mm.q_nn)*(1/sum_p ses)*v[mm][d]
__global__ void k4c_mfma(const u16* __restrict__ qh, const u16* __restrict__ kh,
                         const u16* __restrict__ vth, const float* __restrict__ ses,
                         float* __restrict__ part) {
    int bx = blockIdx.x;
    int p = blockIdx.y;
    int bh = bx >> 5;
    int ntile = bx & 31;
    int nn0 = ntile * 64;
    int b = bh >> 3, h = bh & 7;
    int tid = threadIdx.x, w = tid >> 6, l = tid & 63;
    bf16x8 qf[4];
    #pragma unroll
    for (int nt = 0; nt < 4; ++nt)
        qf[nt] = *(const bf16x8*)&qh[((size_t)bh*MM + nn0 + nt*16 + (l&15))*HD + ((l>>4)<<3)];
    __shared__ u16 Klds[64][40];
    __shared__ u16 Vtlds[32][72];
    __shared__ u16 Wlds[64][72];
    __shared__ float Rlds[64];
    f32x4 o0 = {0.f,0.f,0.f,0.f}, o1 = {0.f,0.f,0.f,0.f};
    int mmbeg = p * (MM/PPB), mmend = mmbeg + (MM/PPB);
    const size_t SESP = (size_t)BB*HH*MM;
    for (int mm0 = mmbeg; mm0 < mmend; mm0 += 64) {
        __syncthreads();
        {
            int r = tid >> 2, ch = tid & 3;
            *(bf16x8*)&Klds[r][ch*8] =
                *(const bf16x8*)&kh[((size_t)bh*MM + mm0 + r)*HD + ch*8];
            int d = tid >> 3, ch2 = tid & 7;
            *(bf16x8*)&Vtlds[d][ch2*8] =
                *(const bf16x8*)&vth[((size_t)bh*HD + d)*MM + mm0 + ch2*8];
            if (tid < 64) {
                size_t e = (size_t)bh*MM + mm0 + tid;
                float s = ses[e] + ses[SESP + e] + ses[2*SESP + e] + ses[3*SESP + e];
                Rlds[tid] = 1.0f / s;
            }
        }
        __syncthreads();
        {
            bf16x8 af = *(const bf16x8*)&Klds[w*16 + (l&15)][(l>>4)<<3];
            float ri[4];
            #pragma unroll
            for (int r = 0; r < 4; ++r) ri[r] = Rlds[w*16 + ((l>>4)<<2) + r];
            #pragma unroll
            for (int nt = 0; nt < 4; ++nt) {
                f32x4 s = {0.f,0.f,0.f,0.f};
                s = __builtin_amdgcn_mfma_f32_16x16x32_bf16(af, qf[nt], s, 0, 0, 0);
                unsigned p0 = (unsigned)f2bfu(__expf(s[0]) * ri[0])
                            | ((unsigned)f2bfu(__expf(s[1]) * ri[1]) << 16);
                unsigned p1 = (unsigned)f2bfu(__expf(s[2]) * ri[2])
                            | ((unsigned)f2bfu(__expf(s[3]) * ri[3]) << 16);
                uint2 pk; pk.x = p0; pk.y = p1;
                *(uint2*)&Wlds[nt*16 + (l&15)][w*16 + ((l>>4)<<2)] = pk;
            }
        }
        __syncthreads();
        #pragma unroll
        for (int ks = 0; ks < 2; ++ks) {
            bf16x8 a2 = *(const bf16x8*)&Wlds[w*16 + (l&15)][ks*32 + ((l>>4)<<3)];
            bf16x8 b20 = *(const bf16x8*)&Vtlds[(l&15)][ks*32 + ((l>>4)<<3)];
            bf16x8 b21 = *(const bf16x8*)&Vtlds[16 + (l&15)][ks*32 + ((l>>4)<<3)];
            o0 = __builtin_amdgcn_mfma_f32_16x16x32_bf16(a2, b20, o0, 0, 0, 0);
            o1 = __builtin_amdgcn_mfma_f32_16x16x32_bf16(a2, b21, o1, 0, 0, 0);
        }
    }
    int nnb = nn0 + w*16 + ((l>>4)<<2);
    int dcol = h*32 + (l&15);
    float* op = part + ((size_t)p*BB + b)*((size_t)MM*CC);
    #pragma unroll
    for (int r = 0; r < 4; ++r) {
        op[((size_t)nnb + r)*CC + dcol]      = o0[r];
        op[((size_t)nnb + r)*CC + dcol + 16] = o1[r];
    }
}

// K5 (MFMA, fused partial reduce): sf2r[b,o,m] = Wproj @ (sum_p part[p]) + bproj
__global__ void k5_mfma(const float* __restrict__ part, const float* __restrict__ wproj,
                        const float* __restrict__ bproj, float* __restrict__ sf2r) {
    int mt = blockIdx.x, ot = blockIdx.y, b = blockIdx.z;
    int mm0 = mt*64, oo0 = ot*64;
    __shared__ u16 S[64][264];
    __shared__ u16 W[64][264];
    int tid = threadIdx.x;
    const size_t PARTP = (size_t)BB*MM*CC;
    const float* pb = part + (size_t)b*MM*CC;
    for (int idx = tid; idx < 64*64; idx += 256) {
        int r = idx >> 6, c4 = (idx & 63) << 2;
        size_t e = (size_t)(mm0 + r)*CC + c4;
        float4 s0 = *(const float4*)&pb[e];
        float4 s1 = *(const float4*)&pb[PARTP + e];
        float4 s2 = *(const float4*)&pb[2*PARTP + e];
        float4 s3 = *(const float4*)&pb[3*PARTP + e];
        float sx = s0.x+s1.x+s2.x+s3.x, sy = s0.y+s1.y+s2.y+s3.y;
        float sz = s0.z+s1.z+s2.z+s3.z, sw = s0.w+s1.w+s2.w+s3.w;
        *(u16x4*)&S[r][c4] = (u16x4){f2bfu(sx), f2bfu(sy), f2bfu(sz), f2bfu(sw)};
        float4 wv = *(const float4*)&wproj[(size_t)(oo0 + r)*CC + c4];
        *(u16x4*)&W[r][c4] = (u16x4){f2bfu(wv.x), f2bfu(wv.y), f2bfu(wv.z), f2bfu(wv.w)};
    }
    __syncthreads();
    int w = tid >> 6, l = tid & 63;
    f32x4 acc[4] = {{0.f,0.f,0.f,0.f},{0.f,0.f,0.f,0.f},{0.f,0.f,0.f,0.f},{0.f,0.f,0.f,0.f}};
    #pragma unroll
    for (int kc = 0; kc < 8; ++kc) {
        bf16x8 bf = *(const bf16x8*)&W[w*16 + (l&15)][kc*32 + ((l>>4)<<3)];
        #pragma unroll
        for (int nt = 0; nt < 4; ++nt) {
            bf16x8 af = *(const bf16x8*)&S[nt*16 + (l&15)][kc*32 + ((l>>4)<<3)];
            acc[nt] = __builtin_amdgcn_mfma_f32_16x16x32_bf16(af, bf, acc[nt], 0, 0, 0);
        }
    }
    int o = oo0 + w*16 + (l&15);
    float bp = bproj[o];
    int m0 = mm0 + ((l>>4)<<2);
    #pragma unroll
    for (int nt = 0; nt < 4; ++nt) {
        #pragma unroll
        for (int r = 0; r < 4; ++r) {
            sf2r[((size_t)b*CC + o)*MM + m0 + nt*16 + r] = acc[nt][r] + bp;
        }
    }
}

// K6: out[b,c,j*16+i] = sum_k sf2r[b,c,j+k-1]*aff[b,j,i,k]  (fp32 output)
// grid = (MM/16, 4 c-quarters, BB); one barrier.
__global__ void k6_final(const float* __restrict__ sf2r, const float* __restrict__ aff,
                         float* __restrict__ out) {
    int jt = blockIdx.x, cq = blockIdx.y, b = blockIdx.z;
    int jb = jt*16, cq0 = cq*64;
    int tid = threadIdx.x;               // 256 tokens
    int jl = tid >> 4, il = tid & 15;
    int j = jb + jl;
    size_t abase = (((size_t)b*MM + j)*SN + il)*3;
    float a0 = aff[abase], a1 = aff[abase+1], a2 = aff[abase+2];
    __shared__ float stile[64][18];
    for (int idx = tid; idx < 64*18; idx += 256) {
        int cl = idx / 18, jo = idx % 18;
        int jj = jb - 1 + jo;
        stile[cl][jo] = (jj >= 0 && jj < MM) ? sf2r[((size_t)b*CC + cq0 + cl)*MM + jj] : 0.f;
    }
    __syncthreads();
    int t = jb*SN + tid;
    float* ob = out + (size_t)b*CC*NN + (size_t)cq0*NN + t;
    #pragma unroll 4
    for (int cl = 0; cl < 64; ++cl) {
        float v = stile[cl][jl]*a0 + stile[cl][jl+1]*a1 + stile[cl][jl+2]*a2;
        ob[(size_t)cl*NN] = v;
    }
}

extern "C" void kernel_launch(void* const* d_in, const int* in_sizes, int n_in,
                              void* d_out, int out_size, void* d_ws, size_t ws_size,
                              hipStream_t stream) {
    const float *x = nullptr, *wqkv = nullptr, *wproj = nullptr, *bproj = nullptr;
    for (int i = 0; i < n_in; ++i) {
        int sz = in_sizes[i];
        if (sz == BB*NN*CC)        x     = (const float*)d_in[i];
        else if (sz == 3*CC*CC)    wqkv  = (const float*)d_in[i];
        else if (sz == CC*CC)      wproj = (const float*)d_in[i];
        else if (sz == CC)         bproj = (const float*)d_in[i];
    }
    float* out = (float*)d_out;    // reference output dtype is float32
    char* ws = (char*)d_ws;
    const size_t MB = 1024*1024;
    // Workspace (32 MiB total)
    float* aff     = (float*)(ws);            // 0.75 MiB (k2 -> k6)
    float* regA    = (float*)(ws + 1*MB);     // 4 MiB: sf (k1->k2), sf2 (k3->k4a)
    u16*   qh      = (u16*)  (ws + 5*MB);     // 2 MiB bf16 [bh][m][32]
    u16*   kh      = (u16*)  (ws + 7*MB);     // 2 MiB bf16 [bh][m][32]
    u16*   vth     = (u16*)  (ws + 9*MB);     // 2 MiB bf16 [bh][32][m]
    float* ses     = (float*)(ws + 11*MB);    // 0.5 MiB (PP1 partials)
    float* sf2r    = (float*)(ws + 12*MB);    // 4 MiB (k5->k6)
    float* part    = (float*)(ws + 16*MB);    // 16 MiB (PPB partials)
    float* sf      = regA;
    float* sf2     = regA;

    k1_sf   <<<BB*MM, 256, 0, stream>>>(x, sf);
    k2_aff  <<<BB*MM, 256, 0, stream>>>(x, sf, aff);
    k3_sf2  <<<BB*MM, 256, 0, stream>>>(x, aff, sf2);
    k4a_mfma<<<dim3(MM/64, 12, BB), 256, 0, stream>>>(sf2, wqkv, qh, kh, vth);
    k4b_mfma<<<dim3(BB*HH*(MM/64), PP1), 256, 0, stream>>>(qh, kh, ses);
    k4c_mfma<<<dim3(BB*HH*(MM/64), PPB), 256, 0, stream>>>(qh, kh, vth, ses, part);
    k5_mfma <<<dim3(MM/64, 4, BB), 256, 0, stream>>>(part, wproj, bproj, sf2r);
    k6_final<<<dim3(MM/16, 4, BB), 256, 0, stream>>>(sf2r, aff, out);
}